// Round 5
// baseline (387.055 us; speedup 1.0000x reference)
//
#include <hip/hip_runtime.h>
#include <cstdint>
#include <cstddef>

#define NEG_SLOPE 0.2f
#define EPS_F 1e-16f

static __device__ __forceinline__ float leaky(float x) { return x > 0.f ? x : NEG_SLOPE * x; }

// ---------------- CSR build ----------------

__global__ __launch_bounds__(256) void hist_k(const int* __restrict__ dst, int* __restrict__ cnt, int E) {
    int i = blockIdx.x * blockDim.x + threadIdx.x;
    if (i < E) atomicAdd(&cnt[dst[i]], 1);
}

__global__ __launch_bounds__(1024) void scan_k(const int* __restrict__ cnt, int* __restrict__ off, int N) {
    __shared__ int wsum[16];
    int tid = threadIdx.x;
    int lane = tid & 63, wid = tid >> 6;
    int running = 0;
    for (int base = 0; base < N; base += 1024) {
        int i = base + tid;
        int v = (i < N) ? cnt[i] : 0;
        int iv = v;
        #pragma unroll
        for (int d = 1; d < 64; d <<= 1) {
            int t = __shfl_up(iv, d);
            if (lane >= d) iv += t;
        }
        if (lane == 63) wsum[wid] = iv;
        __syncthreads();
        if (tid < 16) {
            int s = wsum[tid];
            #pragma unroll
            for (int d = 1; d < 16; d <<= 1) {
                int t = __shfl_up(s, d);
                if (tid >= d) s += t;
            }
            wsum[tid] = s;
        }
        __syncthreads();
        int add = wid ? wsum[wid - 1] : 0;
        if (i < N) off[i + 1] = running + add + iv;
        int ct = wsum[15];
        __syncthreads();
        running += ct;
    }
    if (tid == 0) off[0] = 0;
}

__global__ __launch_bounds__(256) void scat_k(const int* __restrict__ src, const int* __restrict__ dst,
                                              const int* __restrict__ off, int* __restrict__ cnt,
                                              int* __restrict__ esrc, int E) {
    int i = blockIdx.x * blockDim.x + threadIdx.x;
    if (i < E) {
        int d = dst[i];
        int p = off[d] + atomicAdd(&cnt[d], 1);
        esrc[p] = src[i];
    }
}

// ---------------- GEMM with fused alpha epilogue ----------------

template <int M, int H>
__global__ __launch_bounds__(256, 2) void gemm_k(const float* __restrict__ X, const float* __restrict__ W,
                                                 const float* __restrict__ a_s, const float* __restrict__ a_d,
                                                 float* __restrict__ O, float* __restrict__ aS,
                                                 float* __restrict__ aD, int N) {
    constexpr int K = 128, BK = 16, ROWS = 128;
    constexpr int CPT = 8;
    constexpr int CT = M / CPT;
    constexpr int RT = 256 / CT;
    constexpr int RPT = ROWS / RT;
    constexpr int XP = ROWS + 4;
    constexpr int C = M / H;
    constexpr int REDW = C / CPT;
    __shared__ float xsT[BK * XP];
    __shared__ float wt[BK * M];

    const int tid = threadIdx.x;
    const int cc = tid % CT;
    const int rr = tid / CT;
    const int row0 = blockIdx.x * ROWS;

    float acc[RPT][CPT];
    #pragma unroll
    for (int r = 0; r < RPT; ++r)
        #pragma unroll
        for (int j = 0; j < CPT; ++j) acc[r][j] = 0.f;

    for (int k0 = 0; k0 < K; k0 += BK) {
        #pragma unroll
        for (int t = tid; t < ROWS * (BK / 4); t += 256) {
            int r = t >> 2;
            int kk = t & 3;
            int row = row0 + r;
            float4 v = make_float4(0.f, 0.f, 0.f, 0.f);
            if (row < N) v = *reinterpret_cast<const float4*>(&X[(size_t)row * K + k0 + kk * 4]);
            xsT[(kk * 4 + 0) * XP + r] = v.x;
            xsT[(kk * 4 + 1) * XP + r] = v.y;
            xsT[(kk * 4 + 2) * XP + r] = v.z;
            xsT[(kk * 4 + 3) * XP + r] = v.w;
        }
        #pragma unroll
        for (int t = tid; t < BK * (M / 4); t += 256) {
            int c4 = t % (M / 4);
            int k = t / (M / 4);
            *reinterpret_cast<float4*>(&wt[k * M + c4 * 4]) =
                *reinterpret_cast<const float4*>(&W[(size_t)(k0 + k) * M + c4 * 4]);
        }
        __syncthreads();
        #pragma unroll
        for (int k = 0; k < BK; ++k) {
            float xr[RPT];
            #pragma unroll
            for (int r4 = 0; r4 < RPT; r4 += 4) {
                float4 xv = *reinterpret_cast<const float4*>(&xsT[k * XP + rr * RPT + r4]);
                xr[r4 + 0] = xv.x; xr[r4 + 1] = xv.y; xr[r4 + 2] = xv.z; xr[r4 + 3] = xv.w;
            }
            float wv[CPT];
            #pragma unroll
            for (int c4 = 0; c4 < CPT; c4 += 4) {
                float4 w4 = *reinterpret_cast<const float4*>(&wt[k * M + cc * CPT + c4]);
                wv[c4 + 0] = w4.x; wv[c4 + 1] = w4.y; wv[c4 + 2] = w4.z; wv[c4 + 3] = w4.w;
            }
            #pragma unroll
            for (int r = 0; r < RPT; ++r)
                #pragma unroll
                for (int j = 0; j < CPT; ++j)
                    acc[r][j] = fmaf(xr[r], wv[j], acc[r][j]);
        }
        __syncthreads();
    }

    float asr[CPT], adr[CPT];
    #pragma unroll
    for (int c4 = 0; c4 < CPT; c4 += 4) {
        float4 t1 = *reinterpret_cast<const float4*>(a_s + cc * CPT + c4);
        asr[c4 + 0] = t1.x; asr[c4 + 1] = t1.y; asr[c4 + 2] = t1.z; asr[c4 + 3] = t1.w;
        float4 t2 = *reinterpret_cast<const float4*>(a_d + cc * CPT + c4);
        adr[c4 + 0] = t2.x; adr[c4 + 1] = t2.y; adr[c4 + 2] = t2.z; adr[c4 + 3] = t2.w;
    }
    const int head = (cc * CPT) / C;

    #pragma unroll
    for (int r = 0; r < RPT; ++r) {
        int row = row0 + rr * RPT + r;
        float ps = 0.f, pd = 0.f;
        #pragma unroll
        for (int j = 0; j < CPT; ++j) {
            ps = fmaf(acc[r][j], asr[j], ps);
            pd = fmaf(acc[r][j], adr[j], pd);
        }
        #pragma unroll
        for (int d = 1; d < REDW; d <<= 1) {
            ps += __shfl_xor(ps, d);
            pd += __shfl_xor(pd, d);
        }
        if (row < N) {
            #pragma unroll
            for (int c4 = 0; c4 < CPT; c4 += 4)
                *reinterpret_cast<float4*>(&O[(size_t)row * M + cc * CPT + c4]) =
                    make_float4(acc[r][c4], acc[r][c4 + 1], acc[r][c4 + 2], acc[r][c4 + 3]);
            if ((cc & (REDW - 1)) == 0) {
                aS[(size_t)row * H + head] = ps;
                aD[(size_t)row * H + head] = pd;
            }
        }
    }
}

// ---------------- segment-softmax aggregation, one wave per dst node ----------------
// Fast path (deg < 64): single memory epoch — esrc read once per lane, payload
// src ids via __shfl, ALL h-row loads (<=32 per round) issued before the exp/LDS
// weight transpose so everything is in flight concurrently.

template <int H, int C>
__global__ __launch_bounds__(256) void agg_k(const float* __restrict__ h, const float* __restrict__ aS,
                                             const float* __restrict__ aD, const int* __restrict__ off,
                                             const int* __restrict__ esrc, const float* __restrict__ bias,
                                             float* __restrict__ out, int N) {
    constexpr int M = H * C;
    constexpr int CPL = M / 64;  // 2 for M=128, 1 for M=64
    __shared__ float wlds[4][64][H];
    const int wslot = threadIdx.x >> 6;
    int node = (blockIdx.x * blockDim.x + threadIdx.x) >> 6;
    if (node >= N) return;
    const int lane = threadIdx.x & 63;

    float adv[H], asv[H];
    if constexpr (H == 4) {
        float4 t = *reinterpret_cast<const float4*>(aD + (size_t)node * 4);
        adv[0] = t.x; adv[1] = t.y; adv[2] = t.z; adv[3] = t.w;
        float4 u = *reinterpret_cast<const float4*>(aS + (size_t)node * 4);
        asv[0] = u.x; asv[1] = u.y; asv[2] = u.z; asv[3] = u.w;
    } else {
        adv[0] = aD[node]; asv[0] = aS[node];
    }
    float eself[H];
    #pragma unroll
    for (int q = 0; q < H; ++q) eself[q] = leaky(asv[q] + adv[q]);

    const int s0 = off[node], s1 = off[node + 1];
    const int deg = s1 - s0;
    const int ch0 = lane * CPL;
    const int hd = ch0 / C;

    if (deg < 64) {
        const int cnt = deg + 1;  // incl. self loop at slot `deg`
        // one coalesced esrc read; lanes beyond deg alias to self node
        const int svi = s0 + lane;
        const int sv = (svi < s1) ? esrc[svi] : node;

        // ---- round-A prefetch: h rows for edge slots 0..31, ids via shfl ----
        float2 hv2[32];
        float hv1[32];
        if constexpr (CPL == 2) {
            #pragma unroll
            for (int t = 0; t < 32; ++t) {
                int s = __shfl(sv, t);
                hv2[t] = *reinterpret_cast<const float2*>(h + (size_t)s * M + ch0);
            }
        } else {
            #pragma unroll
            for (int t = 0; t < 32; ++t) {
                int s = __shfl(sv, t);
                hv1[t] = h[(size_t)s * M + ch0];
            }
        }

        // ---- weight phase (overlaps h-load latency): exp + LDS transpose ----
        if constexpr (H == 4) {
            float4 u = *reinterpret_cast<const float4*>(aS + (size_t)sv * 4);
            float w0, w1, w2, w3;
            if (lane < deg) {
                w0 = __expf(leaky(u.x + adv[0]));
                w1 = __expf(leaky(u.y + adv[1]));
                w2 = __expf(leaky(u.z + adv[2]));
                w3 = __expf(leaky(u.w + adv[3]));
            } else if (lane == deg) {
                w0 = __expf(eself[0]); w1 = __expf(eself[1]);
                w2 = __expf(eself[2]); w3 = __expf(eself[3]);
            } else {
                w0 = w1 = w2 = w3 = 0.f;
            }
            *reinterpret_cast<float4*>(&wlds[wslot][lane][0]) = make_float4(w0, w1, w2, w3);
        } else {
            float u = aS[sv];
            float w0 = (lane < deg) ? __expf(leaky(u + adv[0]))
                     : (lane == deg) ? __expf(eself[0]) : 0.f;
            wlds[wslot][lane][0] = w0;
        }
        asm volatile("s_waitcnt lgkmcnt(0)" ::: "memory");

        // ---- consume round A ----
        float acc0 = 0.f, acc1 = 0.f, wsum = 0.f;
        #pragma unroll
        for (int t = 0; t < 32; ++t) {
            float wq = wlds[wslot][t][hd];
            wsum += wq;
            if constexpr (CPL == 2) {
                acc0 = fmaf(wq, hv2[t].x, acc0);
                acc1 = fmaf(wq, hv2[t].y, acc1);
            } else {
                acc0 = fmaf(wq, hv1[t], acc0);
            }
        }
        // ---- round B (rare: cnt > 32, ~0.1% of nodes) ----
        if (cnt > 32) {
            if constexpr (CPL == 2) {
                #pragma unroll
                for (int t = 0; t < 32; ++t) {
                    int s = __shfl(sv, 32 + t);
                    hv2[t] = *reinterpret_cast<const float2*>(h + (size_t)s * M + ch0);
                }
                #pragma unroll
                for (int t = 0; t < 32; ++t) {
                    float wq = wlds[wslot][32 + t][hd];
                    wsum += wq;
                    acc0 = fmaf(wq, hv2[t].x, acc0);
                    acc1 = fmaf(wq, hv2[t].y, acc1);
                }
            } else {
                #pragma unroll
                for (int t = 0; t < 32; ++t) {
                    int s = __shfl(sv, 32 + t);
                    hv1[t] = h[(size_t)s * M + ch0];
                }
                #pragma unroll
                for (int t = 0; t < 32; ++t) {
                    float wq = wlds[wslot][32 + t][hd];
                    wsum += wq;
                    acc0 = fmaf(wq, hv1[t], acc0);
                }
            }
        }
        float inv = 1.f / (wsum + EPS_F);
        if constexpr (CPL == 2) {
            float2 o;
            o.x = acc0 * inv + bias[ch0];
            o.y = acc1 * inv + bias[ch0 + 1];
            *reinterpret_cast<float2*>(out + (size_t)node * M + ch0) = o;
        } else {
            out[(size_t)node * M + ch0] = acc0 * inv + bias[ch0];
        }
    } else {
        // ---- fallback (deg >= 64): online softmax + butterfly merge ----
        float m[H], dsum[H];
        #pragma unroll
        for (int q = 0; q < H; ++q) { m[q] = eself[q]; dsum[q] = 0.f; }
        for (int i = s0 + lane; i < s1; i += 64) {
            int s = esrc[i];
            if constexpr (H == 4) {
                float4 u = *reinterpret_cast<const float4*>(aS + (size_t)s * 4);
                float evv[4] = {u.x, u.y, u.z, u.w};
                #pragma unroll
                for (int q = 0; q < 4; ++q) {
                    float e = leaky(evv[q] + adv[q]);
                    float nm = fmaxf(m[q], e);
                    dsum[q] = dsum[q] * __expf(m[q] - nm) + __expf(e - nm);
                    m[q] = nm;
                }
            } else {
                float e = leaky(aS[s] + adv[0]);
                float nm = fmaxf(m[0], e);
                dsum[0] = dsum[0] * __expf(m[0] - nm) + __expf(e - nm);
                m[0] = nm;
            }
        }
        #pragma unroll
        for (int q = 0; q < H; ++q) {
            #pragma unroll
            for (int d = 1; d < 64; d <<= 1) {
                float om = __shfl_xor(m[q], d);
                float od = __shfl_xor(dsum[q], d);
                float nm = fmaxf(m[q], om);
                dsum[q] = dsum[q] * __expf(m[q] - nm) + od * __expf(om - nm);
                m[q] = nm;
            }
            dsum[q] += __expf(eself[q] - m[q]);
        }
        const float advh = adv[hd];
        const float Mh = m[hd];
        float acc0 = 0.f, acc1 = 0.f;
        int i = s0;
        for (; i + 8 <= s1; i += 8) {
            int sv8[8]; float lv[8];
            #pragma unroll
            for (int t = 0; t < 8; ++t) sv8[t] = esrc[i + t];
            #pragma unroll
            for (int t = 0; t < 8; ++t) lv[t] = aS[(size_t)sv8[t] * H + hd];
            if constexpr (CPL == 2) {
                float2 hv[8];
                #pragma unroll
                for (int t = 0; t < 8; ++t) hv[t] = *reinterpret_cast<const float2*>(h + (size_t)sv8[t] * M + ch0);
                #pragma unroll
                for (int t = 0; t < 8; ++t) {
                    float wq = __expf(leaky(lv[t] + advh) - Mh);
                    acc0 = fmaf(wq, hv[t].x, acc0);
                    acc1 = fmaf(wq, hv[t].y, acc1);
                }
            } else {
                float hv[8];
                #pragma unroll
                for (int t = 0; t < 8; ++t) hv[t] = h[(size_t)sv8[t] * M + ch0];
                #pragma unroll
                for (int t = 0; t < 8; ++t) {
                    float wq = __expf(leaky(lv[t] + advh) - Mh);
                    acc0 = fmaf(wq, hv[t], acc0);
                }
            }
        }
        for (; i < s1; ++i) {
            int s = esrc[i];
            float wq = __expf(leaky(aS[(size_t)s * H + hd] + advh) - Mh);
            if constexpr (CPL == 2) {
                float2 hv = *reinterpret_cast<const float2*>(h + (size_t)s * M + ch0);
                acc0 = fmaf(wq, hv.x, acc0);
                acc1 = fmaf(wq, hv.y, acc1);
            } else {
                acc0 = fmaf(wq, h[(size_t)s * M + ch0], acc0);
            }
        }
        {
            float ws = __expf(eself[hd] - Mh);
            if constexpr (CPL == 2) {
                float2 hv = *reinterpret_cast<const float2*>(h + (size_t)node * M + ch0);
                acc0 = fmaf(ws, hv.x, acc0);
                acc1 = fmaf(ws, hv.y, acc1);
            } else {
                acc0 = fmaf(ws, h[(size_t)node * M + ch0], acc0);
            }
        }
        float inv = 1.f / (dsum[hd] + EPS_F);
        if constexpr (CPL == 2) {
            float2 o;
            o.x = acc0 * inv + bias[ch0];
            o.y = acc1 * inv + bias[ch0 + 1];
            *reinterpret_cast<float2*>(out + (size_t)node * M + ch0) = o;
        } else {
            out[(size_t)node * M + ch0] = acc0 * inv + bias[ch0];
        }
    }
}

// ---------------- launch ----------------

extern "C" void kernel_launch(void* const* d_in, const int* in_sizes, int n_in,
                              void* d_out, int out_size, void* d_ws, size_t ws_size,
                              hipStream_t stream) {
    const float* x   = (const float*)d_in[0];
    const int*   ei  = (const int*)d_in[1];
    const float* W0  = (const float*)d_in[2];
    const float* as0 = (const float*)d_in[3];
    const float* ad0 = (const float*)d_in[4];
    const float* b0  = (const float*)d_in[5];
    const float* W1  = (const float*)d_in[6];
    const float* as1 = (const float*)d_in[7];
    const float* ad1 = (const float*)d_in[8];
    const float* b1  = (const float*)d_in[9];
    const float* W2  = (const float*)d_in[10];
    const float* as2 = (const float*)d_in[11];
    const float* ad2 = (const float*)d_in[12];
    const float* b2  = (const float*)d_in[13];

    const int N = in_sizes[0] / 128;  // 50000
    const int E = in_sizes[1] / 2;    // 800000
    const int* esrc_in = ei;
    const int* edst_in = ei + E;

    char* w = (char*)d_ws;
    auto carve = [&](size_t bytes) -> char* {
        char* p = w;
        w += (bytes + 255) & ~(size_t)255;
        return p;
    };
    int*   off  = (int*)carve((size_t)(N + 1) * 4);
    int*   cnt  = (int*)carve((size_t)N * 4);
    int*   es   = (int*)carve((size_t)E * 4);
    float* aS   = (float*)carve((size_t)N * 4 * sizeof(float));
    float* aD   = (float*)carve((size_t)N * 4 * sizeof(float));
    float* bufH = (float*)carve((size_t)N * 128 * sizeof(float));
    float* bufO = (float*)carve((size_t)N * 128 * sizeof(float));
    (void)ws_size; (void)n_in; (void)out_size;

    hipMemsetAsync(cnt, 0, (size_t)N * 4, stream);
    hist_k<<<(E + 255) / 256, 256, 0, stream>>>(edst_in, cnt, E);
    scan_k<<<1, 1024, 0, stream>>>(cnt, off, N);
    hipMemsetAsync(cnt, 0, (size_t)N * 4, stream);
    scat_k<<<(E + 255) / 256, 256, 0, stream>>>(esrc_in, edst_in, off, cnt, es, E);

    const int GEMM_GRID = (N + 127) / 128;
    const int AGG_GRID = (N + 3) / 4;

    gemm_k<128, 4><<<GEMM_GRID, 256, 0, stream>>>(x, W0, as0, ad0, bufH, aS, aD, N);
    agg_k<4, 32><<<AGG_GRID, 256, 0, stream>>>(bufH, aS, aD, off, es, b0, bufO, N);

    gemm_k<128, 4><<<GEMM_GRID, 256, 0, stream>>>(bufO, W1, as1, ad1, bufH, aS, aD, N);
    agg_k<4, 32><<<AGG_GRID, 256, 0, stream>>>(bufH, aS, aD, off, es, b1, bufO, N);

    gemm_k<64, 1><<<GEMM_GRID, 256, 0, stream>>>(bufO, W2, as2, ad2, bufH, aS, aD, N);
    agg_k<1, 64><<<AGG_GRID, 256, 0, stream>>>(bufH, aS, aD, off, es, b2, (float*)d_out, N);
}

// Round 6
// 336.433 us; speedup vs baseline: 1.1505x; 1.1505x over previous
//
#include <hip/hip_runtime.h>
#include <hip/hip_fp16.h>
#include <cstdint>
#include <cstddef>

#define NEG_SLOPE 0.2f
#define EPS_F 1e-16f

static __device__ __forceinline__ float leaky(float x) { return x > 0.f ? x : NEG_SLOPE * x; }

// ---------------- CSR build ----------------

__global__ __launch_bounds__(256) void hist_k(const int* __restrict__ dst, int* __restrict__ cnt, int E) {
    int i = blockIdx.x * blockDim.x + threadIdx.x;
    if (i < E) atomicAdd(&cnt[dst[i]], 1);
}

__global__ __launch_bounds__(1024) void scan_k(const int* __restrict__ cnt, int* __restrict__ off, int N) {
    __shared__ int wsum[16];
    int tid = threadIdx.x;
    int lane = tid & 63, wid = tid >> 6;
    int running = 0;
    for (int base = 0; base < N; base += 1024) {
        int i = base + tid;
        int v = (i < N) ? cnt[i] : 0;
        int iv = v;
        #pragma unroll
        for (int d = 1; d < 64; d <<= 1) {
            int t = __shfl_up(iv, d);
            if (lane >= d) iv += t;
        }
        if (lane == 63) wsum[wid] = iv;
        __syncthreads();
        if (tid < 16) {
            int s = wsum[tid];
            #pragma unroll
            for (int d = 1; d < 16; d <<= 1) {
                int t = __shfl_up(s, d);
                if (tid >= d) s += t;
            }
            wsum[tid] = s;
        }
        __syncthreads();
        int add = wid ? wsum[wid - 1] : 0;
        if (i < N) off[i + 1] = running + add + iv;
        int ct = wsum[15];
        __syncthreads();
        running += ct;
    }
    if (tid == 0) off[0] = 0;
}

__global__ __launch_bounds__(256) void scat_k(const int* __restrict__ src, const int* __restrict__ dst,
                                              const int* __restrict__ off, int* __restrict__ cnt,
                                              int* __restrict__ esrc, int E) {
    int i = blockIdx.x * blockDim.x + threadIdx.x;
    if (i < E) {
        int d = dst[i];
        int p = off[d] + atomicAdd(&cnt[d], 1);
        esrc[p] = src[i];
    }
}

// ---------------- GEMM with fused alpha epilogue; O stored as fp16 ----------------

template <int M, int H>
__global__ __launch_bounds__(256, 2) void gemm_k(const float* __restrict__ X, const float* __restrict__ W,
                                                 const float* __restrict__ a_s, const float* __restrict__ a_d,
                                                 __half* __restrict__ O, float* __restrict__ aS,
                                                 float* __restrict__ aD, int N) {
    constexpr int K = 128, BK = 16, ROWS = 128;
    constexpr int CPT = 8;
    constexpr int CT = M / CPT;
    constexpr int RT = 256 / CT;
    constexpr int RPT = ROWS / RT;
    constexpr int XP = ROWS + 4;
    constexpr int C = M / H;
    constexpr int REDW = C / CPT;
    __shared__ float xsT[BK * XP];
    __shared__ float wt[BK * M];

    const int tid = threadIdx.x;
    const int cc = tid % CT;
    const int rr = tid / CT;
    const int row0 = blockIdx.x * ROWS;

    float acc[RPT][CPT];
    #pragma unroll
    for (int r = 0; r < RPT; ++r)
        #pragma unroll
        for (int j = 0; j < CPT; ++j) acc[r][j] = 0.f;

    for (int k0 = 0; k0 < K; k0 += BK) {
        #pragma unroll
        for (int t = tid; t < ROWS * (BK / 4); t += 256) {
            int r = t >> 2;
            int kk = t & 3;
            int row = row0 + r;
            float4 v = make_float4(0.f, 0.f, 0.f, 0.f);
            if (row < N) v = *reinterpret_cast<const float4*>(&X[(size_t)row * K + k0 + kk * 4]);
            xsT[(kk * 4 + 0) * XP + r] = v.x;
            xsT[(kk * 4 + 1) * XP + r] = v.y;
            xsT[(kk * 4 + 2) * XP + r] = v.z;
            xsT[(kk * 4 + 3) * XP + r] = v.w;
        }
        #pragma unroll
        for (int t = tid; t < BK * (M / 4); t += 256) {
            int c4 = t % (M / 4);
            int k = t / (M / 4);
            *reinterpret_cast<float4*>(&wt[k * M + c4 * 4]) =
                *reinterpret_cast<const float4*>(&W[(size_t)(k0 + k) * M + c4 * 4]);
        }
        __syncthreads();
        #pragma unroll
        for (int k = 0; k < BK; ++k) {
            float xr[RPT];
            #pragma unroll
            for (int r4 = 0; r4 < RPT; r4 += 4) {
                float4 xv = *reinterpret_cast<const float4*>(&xsT[k * XP + rr * RPT + r4]);
                xr[r4 + 0] = xv.x; xr[r4 + 1] = xv.y; xr[r4 + 2] = xv.z; xr[r4 + 3] = xv.w;
            }
            float wv[CPT];
            #pragma unroll
            for (int c4 = 0; c4 < CPT; c4 += 4) {
                float4 w4 = *reinterpret_cast<const float4*>(&wt[k * M + cc * CPT + c4]);
                wv[c4 + 0] = w4.x; wv[c4 + 1] = w4.y; wv[c4 + 2] = w4.z; wv[c4 + 3] = w4.w;
            }
            #pragma unroll
            for (int r = 0; r < RPT; ++r)
                #pragma unroll
                for (int j = 0; j < CPT; ++j)
                    acc[r][j] = fmaf(xr[r], wv[j], acc[r][j]);
        }
        __syncthreads();
    }

    float asr[CPT], adr[CPT];
    #pragma unroll
    for (int c4 = 0; c4 < CPT; c4 += 4) {
        float4 t1 = *reinterpret_cast<const float4*>(a_s + cc * CPT + c4);
        asr[c4 + 0] = t1.x; asr[c4 + 1] = t1.y; asr[c4 + 2] = t1.z; asr[c4 + 3] = t1.w;
        float4 t2 = *reinterpret_cast<const float4*>(a_d + cc * CPT + c4);
        adr[c4 + 0] = t2.x; adr[c4 + 1] = t2.y; adr[c4 + 2] = t2.z; adr[c4 + 3] = t2.w;
    }
    const int head = (cc * CPT) / C;

    #pragma unroll
    for (int r = 0; r < RPT; ++r) {
        int row = row0 + rr * RPT + r;
        float ps = 0.f, pd = 0.f;
        #pragma unroll
        for (int j = 0; j < CPT; ++j) {
            ps = fmaf(acc[r][j], asr[j], ps);
            pd = fmaf(acc[r][j], adr[j], pd);
        }
        #pragma unroll
        for (int d = 1; d < REDW; d <<= 1) {
            ps += __shfl_xor(ps, d);
            pd += __shfl_xor(pd, d);
        }
        if (row < N) {
            __half2 p0 = __float22half2_rn(make_float2(acc[r][0], acc[r][1]));
            __half2 p1 = __float22half2_rn(make_float2(acc[r][2], acc[r][3]));
            __half2 p2 = __float22half2_rn(make_float2(acc[r][4], acc[r][5]));
            __half2 p3 = __float22half2_rn(make_float2(acc[r][6], acc[r][7]));
            uint4 pk;
            pk.x = *reinterpret_cast<unsigned*>(&p0);
            pk.y = *reinterpret_cast<unsigned*>(&p1);
            pk.z = *reinterpret_cast<unsigned*>(&p2);
            pk.w = *reinterpret_cast<unsigned*>(&p3);
            *reinterpret_cast<uint4*>(&O[(size_t)row * M + cc * CPT]) = pk;
            if ((cc & (REDW - 1)) == 0) {
                aS[(size_t)row * H + head] = ps;
                aD[(size_t)row * H + head] = pd;
            }
        }
    }
}

// ---------------- segment-softmax aggregation: 2 nodes per wave, fp16 payload ----------------
// Fast path (deg < 32): 32 lanes per node; per-lane edge logits (no max-sub, logits O(10));
// payload 8-deep double-buffered float4-equivalent fp16 gathers.

template <int H, int C>
__global__ __launch_bounds__(256) void agg_k(const __half* __restrict__ h, const float* __restrict__ aS,
                                             const float* __restrict__ aD, const int* __restrict__ off,
                                             const int* __restrict__ esrc, const float* __restrict__ bias,
                                             float* __restrict__ out, int N) {
    constexpr int M = H * C;
    constexpr int CPL = M / 32;  // channels per lane: 4 (M=128) or 2 (M=64)
    __shared__ float wlds[4][2][32][H];
    __shared__ int   slds[4][2][32];
    const int wslot = threadIdx.x >> 6;
    const int lane  = threadIdx.x & 63;
    const int g     = lane >> 5;
    const int lg    = lane & 31;
    const int node  = (blockIdx.x * 4 + wslot) * 2 + g;
    const bool valid = node < N;
    const int nd = valid ? node : N - 1;

    float adv[H], asv[H];
    if constexpr (H == 4) {
        float4 t = *reinterpret_cast<const float4*>(aD + (size_t)nd * 4);
        adv[0] = t.x; adv[1] = t.y; adv[2] = t.z; adv[3] = t.w;
        float4 u = *reinterpret_cast<const float4*>(aS + (size_t)nd * 4);
        asv[0] = u.x; asv[1] = u.y; asv[2] = u.z; asv[3] = u.w;
    } else {
        adv[0] = aD[nd]; asv[0] = aS[nd];
    }
    float eself[H];
    #pragma unroll
    for (int q = 0; q < H; ++q) eself[q] = leaky(asv[q] + adv[q]);

    const int s0 = off[nd], s1 = off[nd + 1];
    const int deg = s1 - s0;

    if (__all(deg < 32)) {
        // ---- weight phase: one lane per edge (self at slot deg, pad beyond) ----
        const int sv = (lg < deg) ? esrc[s0 + lg] : nd;
        if constexpr (H == 4) {
            float4 u = *reinterpret_cast<const float4*>(aS + (size_t)sv * 4);
            float4 wv;
            if (lg < deg) {
                wv.x = __expf(leaky(u.x + adv[0]));
                wv.y = __expf(leaky(u.y + adv[1]));
                wv.z = __expf(leaky(u.z + adv[2]));
                wv.w = __expf(leaky(u.w + adv[3]));
            } else if (lg == deg) {
                wv = make_float4(__expf(eself[0]), __expf(eself[1]), __expf(eself[2]), __expf(eself[3]));
            } else {
                wv = make_float4(0.f, 0.f, 0.f, 0.f);
            }
            *reinterpret_cast<float4*>(&wlds[wslot][g][lg][0]) = wv;
        } else {
            float u = aS[sv];
            wlds[wslot][g][lg][0] = (lg < deg) ? __expf(leaky(u + adv[0]))
                                  : (lg == deg) ? __expf(eself[0]) : 0.f;
        }
        slds[wslot][g][lg] = sv;
        asm volatile("s_waitcnt lgkmcnt(0)" ::: "memory");

        const int cnt = deg + 1;
        const int cmax = max(cnt, __shfl_xor(cnt, 32));
        const int ch0 = lg * CPL;
        const int hd = ch0 / C;
        float wsum = 0.f;

        if constexpr (CPL == 4) {
            float acc0 = 0.f, acc1 = 0.f, acc2 = 0.f, acc3 = 0.f;
            uint2 A[8], B[8];
            auto issue = [&](uint2 (&buf)[8], int j) {
                #pragma unroll
                for (int t = 0; t < 8; ++t) {
                    int s = slds[wslot][g][j + t];
                    buf[t] = *reinterpret_cast<const uint2*>(h + (size_t)s * M + ch0);
                }
            };
            auto consume = [&](uint2 (&buf)[8], int j) {
                #pragma unroll
                for (int t = 0; t < 8; ++t) {
                    float wq = wlds[wslot][g][j + t][hd];
                    wsum += wq;
                    float2 fa = __half22float2(*reinterpret_cast<__half2*>(&buf[t].x));
                    float2 fb = __half22float2(*reinterpret_cast<__half2*>(&buf[t].y));
                    acc0 = fmaf(wq, fa.x, acc0);
                    acc1 = fmaf(wq, fa.y, acc1);
                    acc2 = fmaf(wq, fb.x, acc2);
                    acc3 = fmaf(wq, fb.y, acc3);
                }
            };
            issue(A, 0);
            if (cmax > 8) issue(B, 8);
            consume(A, 0);
            if (cmax > 8) {
                if (cmax > 16) issue(A, 16);
                consume(B, 8);
                if (cmax > 16) {
                    if (cmax > 24) issue(B, 24);
                    consume(A, 16);
                    if (cmax > 24) consume(B, 24);
                }
            }
            if (valid) {
                float inv = 1.f / (wsum + EPS_F);
                float4 bb = *reinterpret_cast<const float4*>(bias + ch0);
                *reinterpret_cast<float4*>(out + (size_t)nd * M + ch0) =
                    make_float4(acc0 * inv + bb.x, acc1 * inv + bb.y, acc2 * inv + bb.z, acc3 * inv + bb.w);
            }
        } else {
            float acc0 = 0.f, acc1 = 0.f;
            unsigned A[8], B[8];
            auto issue = [&](unsigned (&buf)[8], int j) {
                #pragma unroll
                for (int t = 0; t < 8; ++t) {
                    int s = slds[wslot][g][j + t];
                    buf[t] = *reinterpret_cast<const unsigned*>(h + (size_t)s * M + ch0);
                }
            };
            auto consume = [&](unsigned (&buf)[8], int j) {
                #pragma unroll
                for (int t = 0; t < 8; ++t) {
                    float wq = wlds[wslot][g][j + t][0];
                    wsum += wq;
                    float2 fa = __half22float2(*reinterpret_cast<__half2*>(&buf[t]));
                    acc0 = fmaf(wq, fa.x, acc0);
                    acc1 = fmaf(wq, fa.y, acc1);
                }
            };
            issue(A, 0);
            if (cmax > 8) issue(B, 8);
            consume(A, 0);
            if (cmax > 8) {
                if (cmax > 16) issue(A, 16);
                consume(B, 8);
                if (cmax > 16) {
                    if (cmax > 24) issue(B, 24);
                    consume(A, 16);
                    if (cmax > 24) consume(B, 24);
                }
            }
            if (valid) {
                float inv = 1.f / (wsum + EPS_F);
                float2 bb = *reinterpret_cast<const float2*>(bias + ch0);
                *reinterpret_cast<float2*>(out + (size_t)nd * M + ch0) =
                    make_float2(acc0 * inv + bb.x, acc1 * inv + bb.y);
            }
        }
    } else {
        // ---- rare fallback (any deg >= 32 in the pair): whole wave per node, online softmax ----
        constexpr int CPL64 = M / 64;
        const int ch = lane * CPL64;
        const int hh = ch / C;
        #pragma unroll 1
        for (int i = 0; i < 2; ++i) {
            int fn = (blockIdx.x * 4 + wslot) * 2 + i;
            if (fn >= N) continue;
            float fadv[H], fes[H];
            if constexpr (H == 4) {
                float4 t = *reinterpret_cast<const float4*>(aD + (size_t)fn * 4);
                fadv[0] = t.x; fadv[1] = t.y; fadv[2] = t.z; fadv[3] = t.w;
                float4 u = *reinterpret_cast<const float4*>(aS + (size_t)fn * 4);
                fes[0] = leaky(u.x + t.x); fes[1] = leaky(u.y + t.y);
                fes[2] = leaky(u.z + t.z); fes[3] = leaky(u.w + t.w);
            } else {
                fadv[0] = aD[fn];
                fes[0] = leaky(aS[fn] + fadv[0]);
            }
            int fs0 = off[fn], fs1 = off[fn + 1];
            float m[H], ds[H];
            #pragma unroll
            for (int q = 0; q < H; ++q) { m[q] = fes[q]; ds[q] = 0.f; }
            for (int e = fs0 + lane; e < fs1; e += 64) {
                int s = esrc[e];
                if constexpr (H == 4) {
                    float4 u = *reinterpret_cast<const float4*>(aS + (size_t)s * 4);
                    float evv[4] = {u.x, u.y, u.z, u.w};
                    #pragma unroll
                    for (int q = 0; q < 4; ++q) {
                        float ee = leaky(evv[q] + fadv[q]);
                        float nm = fmaxf(m[q], ee);
                        ds[q] = ds[q] * __expf(m[q] - nm) + __expf(ee - nm);
                        m[q] = nm;
                    }
                } else {
                    float ee = leaky(aS[s] + fadv[0]);
                    float nm = fmaxf(m[0], ee);
                    ds[0] = ds[0] * __expf(m[0] - nm) + __expf(ee - nm);
                    m[0] = nm;
                }
            }
            #pragma unroll
            for (int q = 0; q < H; ++q) {
                #pragma unroll
                for (int d = 1; d < 64; d <<= 1) {
                    float om = __shfl_xor(m[q], d);
                    float od = __shfl_xor(ds[q], d);
                    float nm = fmaxf(m[q], om);
                    ds[q] = ds[q] * __expf(m[q] - nm) + od * __expf(om - nm);
                    m[q] = nm;
                }
                ds[q] += __expf(fes[q] - m[q]);
            }
            float a0 = 0.f, a1 = 0.f;
            for (int e = fs0; e < fs1; ++e) {
                int s = esrc[e];
                float wq = __expf(leaky(aS[(size_t)s * H + hh] + fadv[hh]) - m[hh]);
                if constexpr (CPL64 == 2) {
                    float2 f = __half22float2(*reinterpret_cast<const __half2*>(h + (size_t)s * M + ch));
                    a0 = fmaf(wq, f.x, a0);
                    a1 = fmaf(wq, f.y, a1);
                } else {
                    a0 = fmaf(wq, __half2float(h[(size_t)s * M + ch]), a0);
                }
            }
            {
                float wq = __expf(fes[hh] - m[hh]);
                if constexpr (CPL64 == 2) {
                    float2 f = __half22float2(*reinterpret_cast<const __half2*>(h + (size_t)fn * M + ch));
                    a0 = fmaf(wq, f.x, a0);
                    a1 = fmaf(wq, f.y, a1);
                } else {
                    a0 = fmaf(wq, __half2float(h[(size_t)fn * M + ch]), a0);
                }
            }
            float inv = 1.f / (ds[hh] + EPS_F);
            if constexpr (CPL64 == 2) {
                *reinterpret_cast<float2*>(out + (size_t)fn * M + ch) =
                    make_float2(a0 * inv + bias[ch], a1 * inv + bias[ch + 1]);
            } else {
                out[(size_t)fn * M + ch] = a0 * inv + bias[ch];
            }
        }
    }
}

// ---------------- launch ----------------

extern "C" void kernel_launch(void* const* d_in, const int* in_sizes, int n_in,
                              void* d_out, int out_size, void* d_ws, size_t ws_size,
                              hipStream_t stream) {
    const float* x   = (const float*)d_in[0];
    const int*   ei  = (const int*)d_in[1];
    const float* W0  = (const float*)d_in[2];
    const float* as0 = (const float*)d_in[3];
    const float* ad0 = (const float*)d_in[4];
    const float* b0  = (const float*)d_in[5];
    const float* W1  = (const float*)d_in[6];
    const float* as1 = (const float*)d_in[7];
    const float* ad1 = (const float*)d_in[8];
    const float* b1  = (const float*)d_in[9];
    const float* W2  = (const float*)d_in[10];
    const float* as2 = (const float*)d_in[11];
    const float* ad2 = (const float*)d_in[12];
    const float* b2  = (const float*)d_in[13];

    const int N = in_sizes[0] / 128;  // 50000
    const int E = in_sizes[1] / 2;    // 800000
    const int* esrc_in = ei;
    const int* edst_in = ei + E;

    char* w = (char*)d_ws;
    auto carve = [&](size_t bytes) -> char* {
        char* p = w;
        w += (bytes + 255) & ~(size_t)255;
        return p;
    };
    int*    off  = (int*)carve((size_t)(N + 1) * 4);
    int*    cnt  = (int*)carve((size_t)N * 4);
    int*    es   = (int*)carve((size_t)E * 4);
    float*  aS   = (float*)carve((size_t)N * 4 * sizeof(float));
    float*  aD   = (float*)carve((size_t)N * 4 * sizeof(float));
    __half* bufH = (__half*)carve((size_t)N * 128 * sizeof(__half));
    float*  bufO = (float*)carve((size_t)N * 128 * sizeof(float));
    (void)ws_size; (void)n_in; (void)out_size;

    hipMemsetAsync(cnt, 0, (size_t)N * 4, stream);
    hist_k<<<(E + 255) / 256, 256, 0, stream>>>(edst_in, cnt, E);
    scan_k<<<1, 1024, 0, stream>>>(cnt, off, N);
    hipMemsetAsync(cnt, 0, (size_t)N * 4, stream);
    scat_k<<<(E + 255) / 256, 256, 0, stream>>>(esrc_in, edst_in, off, cnt, es, E);

    const int GEMM_GRID = (N + 127) / 128;
    const int AGG_GRID = (N + 7) / 8;

    gemm_k<128, 4><<<GEMM_GRID, 256, 0, stream>>>(x, W0, as0, ad0, bufH, aS, aD, N);
    agg_k<4, 32><<<AGG_GRID, 256, 0, stream>>>(bufH, aS, aD, off, es, b0, bufO, N);

    gemm_k<128, 4><<<GEMM_GRID, 256, 0, stream>>>(bufO, W1, as1, ad1, bufH, aS, aD, N);
    agg_k<4, 32><<<AGG_GRID, 256, 0, stream>>>(bufH, aS, aD, off, es, b1, bufO, N);

    gemm_k<64, 1><<<GEMM_GRID, 256, 0, stream>>>(bufO, W2, as2, ad2, bufH, aS, aD, N);
    agg_k<1, 64><<<AGG_GRID, 256, 0, stream>>>(bufH, aS, aD, off, es, b2, (float*)d_out, N);
}

// Round 7
// 273.874 us; speedup vs baseline: 1.4133x; 1.2284x over previous
//
#include <hip/hip_runtime.h>
#include <hip/hip_fp16.h>
#include <cstdint>
#include <cstddef>

#define NEG_SLOPE 0.2f
#define EPS_F 1e-16f

static __device__ __forceinline__ float leaky(float x) { return x > 0.f ? x : NEG_SLOPE * x; }

// ---------------- generic single-block exclusive scan: out[0]=0, out[i]=sum(in[0..i-1]) ----------------

__global__ __launch_bounds__(1024) void scan_k(const int* __restrict__ cnt, int* __restrict__ off, int N) {
    __shared__ int wsum[16];
    int tid = threadIdx.x;
    int lane = tid & 63, wid = tid >> 6;
    int running = 0;
    for (int base = 0; base < N; base += 1024) {
        int i = base + tid;
        int v = (i < N) ? cnt[i] : 0;
        int iv = v;
        #pragma unroll
        for (int d = 1; d < 64; d <<= 1) {
            int t = __shfl_up(iv, d);
            if (lane >= d) iv += t;
        }
        if (lane == 63) wsum[wid] = iv;
        __syncthreads();
        if (tid < 16) {
            int s = wsum[tid];
            #pragma unroll
            for (int d = 1; d < 16; d <<= 1) {
                int t = __shfl_up(s, d);
                if (tid >= d) s += t;
            }
            wsum[tid] = s;
        }
        __syncthreads();
        int add = wid ? wsum[wid - 1] : 0;
        if (i < N) off[i + 1] = running + add + iv;
        int ct = wsum[15];
        __syncthreads();
        running += ct;
    }
    if (tid == 0) off[0] = 0;
}

// ---------------- bucketed CSR build ----------------
// partB: scatter edges into block-private runs per bucket (packed src | lowdst<<16)

__global__ __launch_bounds__(256) void partB_k(const int* __restrict__ src, const int* __restrict__ dst,
                                               const int* __restrict__ starts, int* __restrict__ packed,
                                               int E, int nbuk) {
    __shared__ int lcnt[256];
    __shared__ int lbase[256];
    const int blk = blockIdx.x;
    for (int i = threadIdx.x; i < nbuk; i += 256) { lcnt[i] = 0; lbase[i] = starts[i * 256 + blk]; }
    __syncthreads();
    const int chunk = (E + 255) / 256;
    const int base = blk * chunk, end = min(base + chunk, E);
    for (int i = base + (int)threadIdx.x; i < end; i += 256) {
        int d = dst[i], s = src[i];
        int b = d >> 8;
        int slot = atomicAdd(&lcnt[b], 1);
        packed[lbase[b] + slot] = s | ((d & 255) << 16);
    }
}

// partC: per-bucket exact CSR (off + esrc), all writes single-block-local

__global__ __launch_bounds__(256) void partC_k(const int* __restrict__ packed, const int* __restrict__ starts,
                                               int* __restrict__ off, int* __restrict__ esrc,
                                               int N, int E, int nbuk) {
    __shared__ int lcnt[256];
    __shared__ int lpre[256];
    const int b = blockIdx.x;
    const int bstart = starts[b * 256];
    const int bend = (b + 1 < nbuk) ? starts[(b + 1) * 256] : E;
    const int tid = threadIdx.x;
    lcnt[tid] = 0;
    __syncthreads();
    for (int i = bstart + tid; i < bend; i += 256) atomicAdd(&lcnt[packed[i] >> 16], 1);
    __syncthreads();
    if (tid < 64) {
        int v0 = lcnt[tid * 4], v1 = lcnt[tid * 4 + 1], v2 = lcnt[tid * 4 + 2], v3 = lcnt[tid * 4 + 3];
        int s = v0 + v1 + v2 + v3;
        int inc = s;
        #pragma unroll
        for (int d = 1; d < 64; d <<= 1) {
            int t = __shfl_up(inc, d);
            if (tid >= d) inc += t;
        }
        int ex = inc - s;
        lpre[tid * 4] = ex;
        lpre[tid * 4 + 1] = ex + v0;
        lpre[tid * 4 + 2] = ex + v0 + v1;
        lpre[tid * 4 + 3] = ex + v0 + v1 + v2;
    }
    __syncthreads();
    const int n0 = b << 8;
    const int nn = min(256, N - n0);
    if (tid < nn) off[n0 + tid] = bstart + lpre[tid];
    if (b == 0 && tid == 0) off[N] = E;
    lcnt[tid] = 0;
    __syncthreads();
    for (int i = bstart + tid; i < bend; i += 256) {
        int p = packed[i];
        int ld = p >> 16;
        int slot = atomicAdd(&lcnt[ld], 1);
        esrc[bstart + lpre[ld] + slot] = p & 0xFFFF;
    }
}

// ---------------- GEMM body (shared by plain and fused-hist kernels) ----------------

template <int M, int H>
__device__ __forceinline__ void gemm_body(float* xsT, float* wt,
                                          const float* __restrict__ X, const float* __restrict__ W,
                                          const float* __restrict__ a_s, const float* __restrict__ a_d,
                                          __half* __restrict__ O, float* __restrict__ aS,
                                          float* __restrict__ aD, int N, int bid) {
    constexpr int K = 128, BK = 16, ROWS = 128;
    constexpr int CPT = 8;
    constexpr int CT = M / CPT;
    constexpr int RPT = ROWS / (256 / CT);
    constexpr int XP = ROWS + 4;
    constexpr int C = M / H;
    constexpr int REDW = C / CPT;

    const int tid = threadIdx.x;
    const int cc = tid % CT;
    const int rr = tid / CT;
    const int row0 = bid * ROWS;

    float acc[RPT][CPT];
    #pragma unroll
    for (int r = 0; r < RPT; ++r)
        #pragma unroll
        for (int j = 0; j < CPT; ++j) acc[r][j] = 0.f;

    for (int k0 = 0; k0 < K; k0 += BK) {
        #pragma unroll
        for (int t = tid; t < ROWS * (BK / 4); t += 256) {
            int r = t >> 2;
            int kk = t & 3;
            int row = row0 + r;
            float4 v = make_float4(0.f, 0.f, 0.f, 0.f);
            if (row < N) v = *reinterpret_cast<const float4*>(&X[(size_t)row * K + k0 + kk * 4]);
            xsT[(kk * 4 + 0) * XP + r] = v.x;
            xsT[(kk * 4 + 1) * XP + r] = v.y;
            xsT[(kk * 4 + 2) * XP + r] = v.z;
            xsT[(kk * 4 + 3) * XP + r] = v.w;
        }
        #pragma unroll
        for (int t = tid; t < BK * (M / 4); t += 256) {
            int c4 = t % (M / 4);
            int k = t / (M / 4);
            *reinterpret_cast<float4*>(&wt[k * M + c4 * 4]) =
                *reinterpret_cast<const float4*>(&W[(size_t)(k0 + k) * M + c4 * 4]);
        }
        __syncthreads();
        #pragma unroll
        for (int k = 0; k < BK; ++k) {
            float xr[RPT];
            #pragma unroll
            for (int r4 = 0; r4 < RPT; r4 += 4) {
                float4 xv = *reinterpret_cast<const float4*>(&xsT[k * XP + rr * RPT + r4]);
                xr[r4 + 0] = xv.x; xr[r4 + 1] = xv.y; xr[r4 + 2] = xv.z; xr[r4 + 3] = xv.w;
            }
            float wv[CPT];
            #pragma unroll
            for (int c4 = 0; c4 < CPT; c4 += 4) {
                float4 w4 = *reinterpret_cast<const float4*>(&wt[k * M + cc * CPT + c4]);
                wv[c4 + 0] = w4.x; wv[c4 + 1] = w4.y; wv[c4 + 2] = w4.z; wv[c4 + 3] = w4.w;
            }
            #pragma unroll
            for (int r = 0; r < RPT; ++r)
                #pragma unroll
                for (int j = 0; j < CPT; ++j)
                    acc[r][j] = fmaf(xr[r], wv[j], acc[r][j]);
        }
        __syncthreads();
    }

    float asr[CPT], adr[CPT];
    #pragma unroll
    for (int c4 = 0; c4 < CPT; c4 += 4) {
        float4 t1 = *reinterpret_cast<const float4*>(a_s + cc * CPT + c4);
        asr[c4 + 0] = t1.x; asr[c4 + 1] = t1.y; asr[c4 + 2] = t1.z; asr[c4 + 3] = t1.w;
        float4 t2 = *reinterpret_cast<const float4*>(a_d + cc * CPT + c4);
        adr[c4 + 0] = t2.x; adr[c4 + 1] = t2.y; adr[c4 + 2] = t2.z; adr[c4 + 3] = t2.w;
    }
    const int head = (cc * CPT) / C;

    #pragma unroll
    for (int r = 0; r < RPT; ++r) {
        int row = row0 + rr * RPT + r;
        float ps = 0.f, pd = 0.f;
        #pragma unroll
        for (int j = 0; j < CPT; ++j) {
            ps = fmaf(acc[r][j], asr[j], ps);
            pd = fmaf(acc[r][j], adr[j], pd);
        }
        #pragma unroll
        for (int d = 1; d < REDW; d <<= 1) {
            ps += __shfl_xor(ps, d);
            pd += __shfl_xor(pd, d);
        }
        if (row < N) {
            __half2 p0 = __float22half2_rn(make_float2(acc[r][0], acc[r][1]));
            __half2 p1 = __float22half2_rn(make_float2(acc[r][2], acc[r][3]));
            __half2 p2 = __float22half2_rn(make_float2(acc[r][4], acc[r][5]));
            __half2 p3 = __float22half2_rn(make_float2(acc[r][6], acc[r][7]));
            uint4 pk;
            pk.x = *reinterpret_cast<unsigned*>(&p0);
            pk.y = *reinterpret_cast<unsigned*>(&p1);
            pk.z = *reinterpret_cast<unsigned*>(&p2);
            pk.w = *reinterpret_cast<unsigned*>(&p3);
            *reinterpret_cast<uint4*>(&O[(size_t)row * M + cc * CPT]) = pk;
            if ((cc & (REDW - 1)) == 0) {
                aS[(size_t)row * H + head] = ps;
                aD[(size_t)row * H + head] = pd;
            }
        }
    }
}

template <int M, int H>
__global__ __launch_bounds__(256, 2) void gemm_k(const float* __restrict__ X, const float* __restrict__ W,
                                                 const float* __restrict__ a_s, const float* __restrict__ a_d,
                                                 __half* __restrict__ O, float* __restrict__ aS,
                                                 float* __restrict__ aD, int N) {
    __shared__ float smem[16 * 132 + 16 * M];
    gemm_body<M, H>(smem, smem + 16 * 132, X, W, a_s, a_d, O, aS, aD, N, blockIdx.x);
}

// layer-0 GEMM with bucket-histogram blocks appended (independent work, hidden under GEMM)
template <int M, int H>
__global__ __launch_bounds__(256, 2) void gemm_hist_k(const float* __restrict__ X, const float* __restrict__ W,
                                                      const float* __restrict__ a_s, const float* __restrict__ a_d,
                                                      __half* __restrict__ O, float* __restrict__ aS,
                                                      float* __restrict__ aD, int N,
                                                      const int* __restrict__ dst, int E,
                                                      int* __restrict__ cnts, int gemmGrid, int nbuk) {
    __shared__ float smem[16 * 132 + 16 * M];
    if ((int)blockIdx.x < gemmGrid) {
        gemm_body<M, H>(smem, smem + 16 * 132, X, W, a_s, a_d, O, aS, aD, N, blockIdx.x);
    } else {
        int* lcnt = (int*)smem;
        const int blk = blockIdx.x - gemmGrid;
        for (int i = threadIdx.x; i < nbuk; i += 256) lcnt[i] = 0;
        __syncthreads();
        const int chunk = (E + 255) / 256;
        const int base = blk * chunk, end = min(base + chunk, E);
        for (int i = base + (int)threadIdx.x; i < end; i += 256) atomicAdd(&lcnt[dst[i] >> 8], 1);
        __syncthreads();
        for (int b = threadIdx.x; b < nbuk; b += 256) cnts[b * 256 + blk] = lcnt[b];
    }
}

// ---------------- segment-softmax aggregation: 2 nodes per wave, fp16 payload ----------------

template <int H, int C>
__global__ __launch_bounds__(256) void agg_k(const __half* __restrict__ h, const float* __restrict__ aS,
                                             const float* __restrict__ aD, const int* __restrict__ off,
                                             const int* __restrict__ esrc, const float* __restrict__ bias,
                                             float* __restrict__ out, int N) {
    constexpr int M = H * C;
    constexpr int CPL = M / 32;
    __shared__ float wlds[4][2][32][H];
    __shared__ int   slds[4][2][32];
    const int wslot = threadIdx.x >> 6;
    const int lane  = threadIdx.x & 63;
    const int g     = lane >> 5;
    const int lg    = lane & 31;
    const int node  = (blockIdx.x * 4 + wslot) * 2 + g;
    const bool valid = node < N;
    const int nd = valid ? node : N - 1;

    float adv[H], asv[H];
    if constexpr (H == 4) {
        float4 t = *reinterpret_cast<const float4*>(aD + (size_t)nd * 4);
        adv[0] = t.x; adv[1] = t.y; adv[2] = t.z; adv[3] = t.w;
        float4 u = *reinterpret_cast<const float4*>(aS + (size_t)nd * 4);
        asv[0] = u.x; asv[1] = u.y; asv[2] = u.z; asv[3] = u.w;
    } else {
        adv[0] = aD[nd]; asv[0] = aS[nd];
    }
    float eself[H];
    #pragma unroll
    for (int q = 0; q < H; ++q) eself[q] = leaky(asv[q] + adv[q]);

    const int s0 = off[nd], s1 = off[nd + 1];
    const int deg = s1 - s0;

    if (__all(deg < 32)) {
        const int sv = (lg < deg) ? esrc[s0 + lg] : nd;
        if constexpr (H == 4) {
            float4 u = *reinterpret_cast<const float4*>(aS + (size_t)sv * 4);
            float4 wv;
            if (lg < deg) {
                wv.x = __expf(leaky(u.x + adv[0]));
                wv.y = __expf(leaky(u.y + adv[1]));
                wv.z = __expf(leaky(u.z + adv[2]));
                wv.w = __expf(leaky(u.w + adv[3]));
            } else if (lg == deg) {
                wv = make_float4(__expf(eself[0]), __expf(eself[1]), __expf(eself[2]), __expf(eself[3]));
            } else {
                wv = make_float4(0.f, 0.f, 0.f, 0.f);
            }
            *reinterpret_cast<float4*>(&wlds[wslot][g][lg][0]) = wv;
        } else {
            float u = aS[sv];
            wlds[wslot][g][lg][0] = (lg < deg) ? __expf(leaky(u + adv[0]))
                                  : (lg == deg) ? __expf(eself[0]) : 0.f;
        }
        slds[wslot][g][lg] = sv;
        asm volatile("s_waitcnt lgkmcnt(0)" ::: "memory");

        const int cnt = deg + 1;
        const int cmax = max(cnt, __shfl_xor(cnt, 32));
        const int ch0 = lg * CPL;
        const int hd = ch0 / C;
        float wsum = 0.f;

        if constexpr (CPL == 4) {
            float acc0 = 0.f, acc1 = 0.f, acc2 = 0.f, acc3 = 0.f;
            uint2 A[8], B[8];
            auto issue = [&](uint2 (&buf)[8], int j) {
                #pragma unroll
                for (int t = 0; t < 8; ++t) {
                    int s = slds[wslot][g][j + t];
                    buf[t] = *reinterpret_cast<const uint2*>(h + (size_t)s * M + ch0);
                }
            };
            auto consume = [&](uint2 (&buf)[8], int j) {
                #pragma unroll
                for (int t = 0; t < 8; ++t) {
                    float wq = wlds[wslot][g][j + t][hd];
                    wsum += wq;
                    float2 fa = __half22float2(*reinterpret_cast<__half2*>(&buf[t].x));
                    float2 fb = __half22float2(*reinterpret_cast<__half2*>(&buf[t].y));
                    acc0 = fmaf(wq, fa.x, acc0);
                    acc1 = fmaf(wq, fa.y, acc1);
                    acc2 = fmaf(wq, fb.x, acc2);
                    acc3 = fmaf(wq, fb.y, acc3);
                }
            };
            issue(A, 0);
            if (cmax > 8) issue(B, 8);
            consume(A, 0);
            if (cmax > 8) {
                if (cmax > 16) issue(A, 16);
                consume(B, 8);
                if (cmax > 16) {
                    if (cmax > 24) issue(B, 24);
                    consume(A, 16);
                    if (cmax > 24) consume(B, 24);
                }
            }
            if (valid) {
                float inv = 1.f / (wsum + EPS_F);
                float4 bb = *reinterpret_cast<const float4*>(bias + ch0);
                *reinterpret_cast<float4*>(out + (size_t)nd * M + ch0) =
                    make_float4(acc0 * inv + bb.x, acc1 * inv + bb.y, acc2 * inv + bb.z, acc3 * inv + bb.w);
            }
        } else {
            float acc0 = 0.f, acc1 = 0.f;
            unsigned A[8], B[8];
            auto issue = [&](unsigned (&buf)[8], int j) {
                #pragma unroll
                for (int t = 0; t < 8; ++t) {
                    int s = slds[wslot][g][j + t];
                    buf[t] = *reinterpret_cast<const unsigned*>(h + (size_t)s * M + ch0);
                }
            };
            auto consume = [&](unsigned (&buf)[8], int j) {
                #pragma unroll
                for (int t = 0; t < 8; ++t) {
                    float wq = wlds[wslot][g][j + t][0];
                    wsum += wq;
                    float2 fa = __half22float2(*reinterpret_cast<__half2*>(&buf[t]));
                    acc0 = fmaf(wq, fa.x, acc0);
                    acc1 = fmaf(wq, fa.y, acc1);
                }
            };
            issue(A, 0);
            if (cmax > 8) issue(B, 8);
            consume(A, 0);
            if (cmax > 8) {
                if (cmax > 16) issue(A, 16);
                consume(B, 8);
                if (cmax > 16) {
                    if (cmax > 24) issue(B, 24);
                    consume(A, 16);
                    if (cmax > 24) consume(B, 24);
                }
            }
            if (valid) {
                float inv = 1.f / (wsum + EPS_F);
                float2 bb = *reinterpret_cast<const float2*>(bias + ch0);
                *reinterpret_cast<float2*>(out + (size_t)nd * M + ch0) =
                    make_float2(acc0 * inv + bb.x, acc1 * inv + bb.y);
            }
        }
    } else {
        constexpr int CPL64 = M / 64;
        const int ch = lane * CPL64;
        const int hh = ch / C;
        #pragma unroll 1
        for (int i = 0; i < 2; ++i) {
            int fn = (blockIdx.x * 4 + wslot) * 2 + i;
            if (fn >= N) continue;
            float fadv[H], fes[H];
            if constexpr (H == 4) {
                float4 t = *reinterpret_cast<const float4*>(aD + (size_t)fn * 4);
                fadv[0] = t.x; fadv[1] = t.y; fadv[2] = t.z; fadv[3] = t.w;
                float4 u = *reinterpret_cast<const float4*>(aS + (size_t)fn * 4);
                fes[0] = leaky(u.x + t.x); fes[1] = leaky(u.y + t.y);
                fes[2] = leaky(u.z + t.z); fes[3] = leaky(u.w + t.w);
            } else {
                fadv[0] = aD[fn];
                fes[0] = leaky(aS[fn] + fadv[0]);
            }
            int fs0 = off[fn], fs1 = off[fn + 1];
            float m[H], ds[H];
            #pragma unroll
            for (int q = 0; q < H; ++q) { m[q] = fes[q]; ds[q] = 0.f; }
            for (int e = fs0 + lane; e < fs1; e += 64) {
                int s = esrc[e];
                if constexpr (H == 4) {
                    float4 u = *reinterpret_cast<const float4*>(aS + (size_t)s * 4);
                    float evv[4] = {u.x, u.y, u.z, u.w};
                    #pragma unroll
                    for (int q = 0; q < 4; ++q) {
                        float ee = leaky(evv[q] + fadv[q]);
                        float nm = fmaxf(m[q], ee);
                        ds[q] = ds[q] * __expf(m[q] - nm) + __expf(ee - nm);
                        m[q] = nm;
                    }
                } else {
                    float ee = leaky(aS[s] + fadv[0]);
                    float nm = fmaxf(m[0], ee);
                    ds[0] = ds[0] * __expf(m[0] - nm) + __expf(ee - nm);
                    m[0] = nm;
                }
            }
            #pragma unroll
            for (int q = 0; q < H; ++q) {
                #pragma unroll
                for (int d = 1; d < 64; d <<= 1) {
                    float om = __shfl_xor(m[q], d);
                    float od = __shfl_xor(ds[q], d);
                    float nm = fmaxf(m[q], om);
                    ds[q] = ds[q] * __expf(m[q] - nm) + od * __expf(om - nm);
                    m[q] = nm;
                }
                ds[q] += __expf(fes[q] - m[q]);
            }
            float a0 = 0.f, a1 = 0.f;
            for (int e = fs0; e < fs1; ++e) {
                int s = esrc[e];
                float wq = __expf(leaky(aS[(size_t)s * H + hh] + fadv[hh]) - m[hh]);
                if constexpr (CPL64 == 2) {
                    float2 f = __half22float2(*reinterpret_cast<const __half2*>(h + (size_t)s * M + ch));
                    a0 = fmaf(wq, f.x, a0);
                    a1 = fmaf(wq, f.y, a1);
                } else {
                    a0 = fmaf(wq, __half2float(h[(size_t)s * M + ch]), a0);
                }
            }
            {
                float wq = __expf(fes[hh] - m[hh]);
                if constexpr (CPL64 == 2) {
                    float2 f = __half22float2(*reinterpret_cast<const __half2*>(h + (size_t)fn * M + ch));
                    a0 = fmaf(wq, f.x, a0);
                    a1 = fmaf(wq, f.y, a1);
                } else {
                    a0 = fmaf(wq, __half2float(h[(size_t)fn * M + ch]), a0);
                }
            }
            float inv = 1.f / (ds[hh] + EPS_F);
            if constexpr (CPL64 == 2) {
                *reinterpret_cast<float2*>(out + (size_t)fn * M + ch) =
                    make_float2(a0 * inv + bias[ch], a1 * inv + bias[ch + 1]);
            } else {
                out[(size_t)fn * M + ch] = a0 * inv + bias[ch];
            }
        }
    }
}

// ---------------- launch ----------------

extern "C" void kernel_launch(void* const* d_in, const int* in_sizes, int n_in,
                              void* d_out, int out_size, void* d_ws, size_t ws_size,
                              hipStream_t stream) {
    const float* x   = (const float*)d_in[0];
    const int*   ei  = (const int*)d_in[1];
    const float* W0  = (const float*)d_in[2];
    const float* as0 = (const float*)d_in[3];
    const float* ad0 = (const float*)d_in[4];
    const float* b0  = (const float*)d_in[5];
    const float* W1  = (const float*)d_in[6];
    const float* as1 = (const float*)d_in[7];
    const float* ad1 = (const float*)d_in[8];
    const float* b1  = (const float*)d_in[9];
    const float* W2  = (const float*)d_in[10];
    const float* as2 = (const float*)d_in[11];
    const float* ad2 = (const float*)d_in[12];
    const float* b2  = (const float*)d_in[13];

    const int N = in_sizes[0] / 128;  // 50000
    const int E = in_sizes[1] / 2;    // 800000
    const int* esrc_in = ei;
    const int* edst_in = ei + E;
    const int NBUK = (N + 255) >> 8;  // 196
    const int NBLKB = 256;

    char* w = (char*)d_ws;
    auto carve = [&](size_t bytes) -> char* {
        char* p = w;
        w += (bytes + 255) & ~(size_t)255;
        return p;
    };
    int*    off    = (int*)carve((size_t)(N + 1) * 4);
    int*    es     = (int*)carve((size_t)E * 4);
    int*    cnts   = (int*)carve((size_t)NBUK * NBLKB * 4);
    int*    starts = (int*)carve(((size_t)NBUK * NBLKB + 1) * 4);
    int*    packed = (int*)carve((size_t)E * 4);
    float*  aS     = (float*)carve((size_t)N * 4 * sizeof(float));
    float*  aD     = (float*)carve((size_t)N * 4 * sizeof(float));
    __half* bufH   = (__half*)carve((size_t)N * 128 * sizeof(__half));
    float*  bufO   = (float*)carve((size_t)N * 128 * sizeof(float));
    (void)ws_size; (void)n_in; (void)out_size;

    const int GEMM_GRID = (N + 127) / 128;
    const int AGG_GRID = (N + 7) / 8;

    // layer-0 GEMM + bucket histogram (fused, independent work)
    gemm_hist_k<128, 4><<<GEMM_GRID + NBLKB, 256, 0, stream>>>(x, W0, as0, ad0, bufH, aS, aD, N,
                                                               edst_in, E, cnts, GEMM_GRID, NBUK);
    scan_k<<<1, 1024, 0, stream>>>(cnts, starts, NBUK * NBLKB);
    partB_k<<<NBLKB, 256, 0, stream>>>(esrc_in, edst_in, starts, packed, E, NBUK);
    partC_k<<<NBUK, 256, 0, stream>>>(packed, starts, off, es, N, E, NBUK);

    agg_k<4, 32><<<AGG_GRID, 256, 0, stream>>>(bufH, aS, aD, off, es, b0, bufO, N);

    gemm_k<128, 4><<<GEMM_GRID, 256, 0, stream>>>(bufO, W1, as1, ad1, bufH, aS, aD, N);
    agg_k<4, 32><<<AGG_GRID, 256, 0, stream>>>(bufH, aS, aD, off, es, b1, bufO, N);

    gemm_k<64, 1><<<GEMM_GRID, 256, 0, stream>>>(bufO, W2, as2, ad2, bufH, aS, aD, N);
    agg_k<1, 64><<<AGG_GRID, 256, 0, stream>>>(bufH, aS, aD, off, es, b2, (float*)d_out, N);
}

// Round 8
// 271.474 us; speedup vs baseline: 1.4258x; 1.0088x over previous
//
#include <hip/hip_runtime.h>
#include <hip/hip_fp16.h>
#include <cstdint>
#include <cstddef>

#define NEG_SLOPE 0.2f
#define EPS_F 1e-16f

static __device__ __forceinline__ float leaky(float x) { return x > 0.f ? x : NEG_SLOPE * x; }

// ---------------- generic single-block exclusive scan ----------------

__global__ __launch_bounds__(1024) void scan_k(const int* __restrict__ cnt, int* __restrict__ off, int N) {
    __shared__ int wsum[16];
    int tid = threadIdx.x;
    int lane = tid & 63, wid = tid >> 6;
    int running = 0;
    for (int base = 0; base < N; base += 1024) {
        int i = base + tid;
        int v = (i < N) ? cnt[i] : 0;
        int iv = v;
        #pragma unroll
        for (int d = 1; d < 64; d <<= 1) {
            int t = __shfl_up(iv, d);
            if (lane >= d) iv += t;
        }
        if (lane == 63) wsum[wid] = iv;
        __syncthreads();
        if (tid < 16) {
            int s = wsum[tid];
            #pragma unroll
            for (int d = 1; d < 16; d <<= 1) {
                int t = __shfl_up(s, d);
                if (tid >= d) s += t;
            }
            wsum[tid] = s;
        }
        __syncthreads();
        int add = wid ? wsum[wid - 1] : 0;
        if (i < N) off[i + 1] = running + add + iv;
        int ct = wsum[15];
        __syncthreads();
        running += ct;
    }
    if (tid == 0) off[0] = 0;
}

// ---------------- bucketed CSR build ----------------

__global__ __launch_bounds__(256) void partB_k(const int* __restrict__ src, const int* __restrict__ dst,
                                               const int* __restrict__ starts, int* __restrict__ packed,
                                               int E, int nbuk) {
    __shared__ int lcnt[256];
    __shared__ int lbase[256];
    const int blk = blockIdx.x;
    for (int i = threadIdx.x; i < nbuk; i += 256) { lcnt[i] = 0; lbase[i] = starts[i * 256 + blk]; }
    __syncthreads();
    const int chunk = (E + 255) / 256;
    const int base = blk * chunk, end = min(base + chunk, E);
    for (int i = base + (int)threadIdx.x; i < end; i += 256) {
        int d = dst[i], s = src[i];
        int b = d >> 8;
        int slot = atomicAdd(&lcnt[b], 1);
        packed[lbase[b] + slot] = s | ((d & 255) << 16);
    }
}

__global__ __launch_bounds__(256) void partC_k(const int* __restrict__ packed, const int* __restrict__ starts,
                                               int* __restrict__ off, int* __restrict__ esrc,
                                               int N, int E, int nbuk) {
    __shared__ int lcnt[256];
    __shared__ int lpre[256];
    const int b = blockIdx.x;
    const int bstart = starts[b * 256];
    const int bend = (b + 1 < nbuk) ? starts[(b + 1) * 256] : E;
    const int tid = threadIdx.x;
    lcnt[tid] = 0;
    __syncthreads();
    for (int i = bstart + tid; i < bend; i += 256) atomicAdd(&lcnt[packed[i] >> 16], 1);
    __syncthreads();
    if (tid < 64) {
        int v0 = lcnt[tid * 4], v1 = lcnt[tid * 4 + 1], v2 = lcnt[tid * 4 + 2], v3 = lcnt[tid * 4 + 3];
        int s = v0 + v1 + v2 + v3;
        int inc = s;
        #pragma unroll
        for (int d = 1; d < 64; d <<= 1) {
            int t = __shfl_up(inc, d);
            if (tid >= d) inc += t;
        }
        int ex = inc - s;
        lpre[tid * 4] = ex;
        lpre[tid * 4 + 1] = ex + v0;
        lpre[tid * 4 + 2] = ex + v0 + v1;
        lpre[tid * 4 + 3] = ex + v0 + v1 + v2;
    }
    __syncthreads();
    const int n0 = b << 8;
    const int nn = min(256, N - n0);
    if (tid < nn) off[n0 + tid] = bstart + lpre[tid];
    if (b == 0 && tid == 0) off[N] = E;
    lcnt[tid] = 0;
    __syncthreads();
    for (int i = bstart + tid; i < bend; i += 256) {
        int p = packed[i];
        int ld = p >> 16;
        int slot = atomicAdd(&lcnt[ld], 1);
        esrc[bstart + lpre[ld] + slot] = p & 0xFFFF;
    }
}

// ---------------- GEMM body (templated input type) ----------------

template <int M, int H, typename XT>
__device__ __forceinline__ void gemm_body(float* xsT, float* wt,
                                          const XT* __restrict__ X, const float* __restrict__ W,
                                          const float* __restrict__ a_s, const float* __restrict__ a_d,
                                          __half* __restrict__ O, float* __restrict__ aS,
                                          float* __restrict__ aD, int N, int bid) {
    constexpr int K = 128, BK = 16, ROWS = 128;
    constexpr int CPT = 8;
    constexpr int CT = M / CPT;
    constexpr int RPT = ROWS / (256 / CT);
    constexpr int XP = ROWS + 4;
    constexpr int C = M / H;
    constexpr int REDW = C / CPT;

    const int tid = threadIdx.x;
    const int cc = tid % CT;
    const int rr = tid / CT;
    const int row0 = bid * ROWS;

    float acc[RPT][CPT];
    #pragma unroll
    for (int r = 0; r < RPT; ++r)
        #pragma unroll
        for (int j = 0; j < CPT; ++j) acc[r][j] = 0.f;

    for (int k0 = 0; k0 < K; k0 += BK) {
        #pragma unroll
        for (int t = tid; t < ROWS * (BK / 4); t += 256) {
            int r = t >> 2;
            int kk = t & 3;
            int row = row0 + r;
            float4 v = make_float4(0.f, 0.f, 0.f, 0.f);
            if (row < N) {
                if constexpr (sizeof(XT) == 2) {
                    uint2 raw = *reinterpret_cast<const uint2*>(&X[(size_t)row * K + k0 + kk * 4]);
                    float2 fa = __half22float2(*reinterpret_cast<__half2*>(&raw.x));
                    float2 fb = __half22float2(*reinterpret_cast<__half2*>(&raw.y));
                    v = make_float4(fa.x, fa.y, fb.x, fb.y);
                } else {
                    v = *reinterpret_cast<const float4*>(&X[(size_t)row * K + k0 + kk * 4]);
                }
            }
            xsT[(kk * 4 + 0) * XP + r] = v.x;
            xsT[(kk * 4 + 1) * XP + r] = v.y;
            xsT[(kk * 4 + 2) * XP + r] = v.z;
            xsT[(kk * 4 + 3) * XP + r] = v.w;
        }
        #pragma unroll
        for (int t = tid; t < BK * (M / 4); t += 256) {
            int c4 = t % (M / 4);
            int k = t / (M / 4);
            *reinterpret_cast<float4*>(&wt[k * M + c4 * 4]) =
                *reinterpret_cast<const float4*>(&W[(size_t)(k0 + k) * M + c4 * 4]);
        }
        __syncthreads();
        #pragma unroll
        for (int k = 0; k < BK; ++k) {
            float xr[RPT];
            #pragma unroll
            for (int r4 = 0; r4 < RPT; r4 += 4) {
                float4 xv = *reinterpret_cast<const float4*>(&xsT[k * XP + rr * RPT + r4]);
                xr[r4 + 0] = xv.x; xr[r4 + 1] = xv.y; xr[r4 + 2] = xv.z; xr[r4 + 3] = xv.w;
            }
            float wv[CPT];
            #pragma unroll
            for (int c4 = 0; c4 < CPT; c4 += 4) {
                float4 w4 = *reinterpret_cast<const float4*>(&wt[k * M + cc * CPT + c4]);
                wv[c4 + 0] = w4.x; wv[c4 + 1] = w4.y; wv[c4 + 2] = w4.z; wv[c4 + 3] = w4.w;
            }
            #pragma unroll
            for (int r = 0; r < RPT; ++r)
                #pragma unroll
                for (int j = 0; j < CPT; ++j)
                    acc[r][j] = fmaf(xr[r], wv[j], acc[r][j]);
        }
        __syncthreads();
    }

    float asr[CPT], adr[CPT];
    #pragma unroll
    for (int c4 = 0; c4 < CPT; c4 += 4) {
        float4 t1 = *reinterpret_cast<const float4*>(a_s + cc * CPT + c4);
        asr[c4 + 0] = t1.x; asr[c4 + 1] = t1.y; asr[c4 + 2] = t1.z; asr[c4 + 3] = t1.w;
        float4 t2 = *reinterpret_cast<const float4*>(a_d + cc * CPT + c4);
        adr[c4 + 0] = t2.x; adr[c4 + 1] = t2.y; adr[c4 + 2] = t2.z; adr[c4 + 3] = t2.w;
    }
    const int head = (cc * CPT) / C;

    #pragma unroll
    for (int r = 0; r < RPT; ++r) {
        int row = row0 + rr * RPT + r;
        float ps = 0.f, pd = 0.f;
        #pragma unroll
        for (int j = 0; j < CPT; ++j) {
            ps = fmaf(acc[r][j], asr[j], ps);
            pd = fmaf(acc[r][j], adr[j], pd);
        }
        #pragma unroll
        for (int d = 1; d < REDW; d <<= 1) {
            ps += __shfl_xor(ps, d);
            pd += __shfl_xor(pd, d);
        }
        if (row < N) {
            __half2 p0 = __float22half2_rn(make_float2(acc[r][0], acc[r][1]));
            __half2 p1 = __float22half2_rn(make_float2(acc[r][2], acc[r][3]));
            __half2 p2 = __float22half2_rn(make_float2(acc[r][4], acc[r][5]));
            __half2 p3 = __float22half2_rn(make_float2(acc[r][6], acc[r][7]));
            uint4 pk;
            pk.x = *reinterpret_cast<unsigned*>(&p0);
            pk.y = *reinterpret_cast<unsigned*>(&p1);
            pk.z = *reinterpret_cast<unsigned*>(&p2);
            pk.w = *reinterpret_cast<unsigned*>(&p3);
            *reinterpret_cast<uint4*>(&O[(size_t)row * M + cc * CPT]) = pk;
            if ((cc & (REDW - 1)) == 0) {
                aS[(size_t)row * H + head] = ps;
                aD[(size_t)row * H + head] = pd;
            }
        }
    }
}

template <int M, int H, typename XT>
__global__ __launch_bounds__(256, 2) void gemm_k(const XT* __restrict__ X, const float* __restrict__ W,
                                                 const float* __restrict__ a_s, const float* __restrict__ a_d,
                                                 __half* __restrict__ O, float* __restrict__ aS,
                                                 float* __restrict__ aD, int N) {
    __shared__ float smem[16 * 132 + 16 * M];
    gemm_body<M, H, XT>(smem, smem + 16 * 132, X, W, a_s, a_d, O, aS, aD, N, blockIdx.x);
}

template <int M, int H>
__global__ __launch_bounds__(256, 2) void gemm_hist_k(const float* __restrict__ X, const float* __restrict__ W,
                                                      const float* __restrict__ a_s, const float* __restrict__ a_d,
                                                      __half* __restrict__ O, float* __restrict__ aS,
                                                      float* __restrict__ aD, int N,
                                                      const int* __restrict__ dst, int E,
                                                      int* __restrict__ cnts, int gemmGrid, int nbuk) {
    __shared__ float smem[16 * 132 + 16 * M];
    if ((int)blockIdx.x < gemmGrid) {
        gemm_body<M, H, float>(smem, smem + 16 * 132, X, W, a_s, a_d, O, aS, aD, N, blockIdx.x);
    } else {
        int* lcnt = (int*)smem;
        const int blk = blockIdx.x - gemmGrid;
        for (int i = threadIdx.x; i < nbuk; i += 256) lcnt[i] = 0;
        __syncthreads();
        const int chunk = (E + 255) / 256;
        const int base = blk * chunk, end = min(base + chunk, E);
        for (int i = base + (int)threadIdx.x; i < end; i += 256) atomicAdd(&lcnt[dst[i] >> 8], 1);
        __syncthreads();
        for (int b = threadIdx.x; b < nbuk; b += 256) cnts[b * 256 + blk] = lcnt[b];
    }
}

// ---------------- segment-softmax aggregation: 2 nodes per wave, fp16 payload ----------------
// Fast path: batch-0 h-ids come from __shfl of the per-lane esrc value, so the h-gathers
// issue concurrently with the aS gather; the exp+LDS weight phase hides under them.

template <int H, int C, typename OutT>
__global__ __launch_bounds__(256) void agg_k(const __half* __restrict__ h, const float* __restrict__ aS,
                                             const float* __restrict__ aD, const int* __restrict__ off,
                                             const int* __restrict__ esrc, const float* __restrict__ bias,
                                             OutT* __restrict__ out, int N) {
    constexpr int M = H * C;
    constexpr int CPL = M / 32;
    __shared__ float wlds[4][2][32][H];
    __shared__ int   slds[4][2][32];
    const int wslot = threadIdx.x >> 6;
    const int lane  = threadIdx.x & 63;
    const int g     = lane >> 5;
    const int lg    = lane & 31;
    const int node  = (blockIdx.x * 4 + wslot) * 2 + g;
    const bool valid = node < N;
    const int nd = valid ? node : N - 1;

    float adv[H], asv[H];
    if constexpr (H == 4) {
        float4 t = *reinterpret_cast<const float4*>(aD + (size_t)nd * 4);
        adv[0] = t.x; adv[1] = t.y; adv[2] = t.z; adv[3] = t.w;
        float4 u = *reinterpret_cast<const float4*>(aS + (size_t)nd * 4);
        asv[0] = u.x; asv[1] = u.y; asv[2] = u.z; asv[3] = u.w;
    } else {
        adv[0] = aD[nd]; asv[0] = aS[nd];
    }
    float eself[H];
    #pragma unroll
    for (int q = 0; q < H; ++q) eself[q] = leaky(asv[q] + adv[q]);

    const int s0 = off[nd], s1 = off[nd + 1];
    const int deg = s1 - s0;

    if (__all(deg < 32)) {
        const int sv = (lg < deg) ? esrc[s0 + lg] : nd;
        const int ch0 = lg * CPL;
        const int hd = ch0 / C;
        const int cnt = deg + 1;
        const int cmax = max(cnt, __shfl_xor(cnt, 32));
        float wsum = 0.f;

        if constexpr (CPL == 4) {
            uint2 A[8], B[8];
            // batch-0 h loads via shfl — issue before the weight phase completes
            #pragma unroll
            for (int t = 0; t < 8; ++t) {
                int s = __shfl(sv, t, 32);
                A[t] = *reinterpret_cast<const uint2*>(h + (size_t)s * M + ch0);
            }
            // weight phase (overlaps the h loads)
            {
                float4 u = *reinterpret_cast<const float4*>(aS + (size_t)sv * 4);
                float4 wv;
                if (lg < deg) {
                    wv.x = __expf(leaky(u.x + adv[0]));
                    wv.y = __expf(leaky(u.y + adv[1]));
                    wv.z = __expf(leaky(u.z + adv[2]));
                    wv.w = __expf(leaky(u.w + adv[3]));
                } else if (lg == deg) {
                    wv = make_float4(__expf(eself[0]), __expf(eself[1]), __expf(eself[2]), __expf(eself[3]));
                } else {
                    wv = make_float4(0.f, 0.f, 0.f, 0.f);
                }
                *reinterpret_cast<float4*>(&wlds[wslot][g][lg][0]) = wv;
                slds[wslot][g][lg] = sv;
            }
            asm volatile("s_waitcnt lgkmcnt(0)" ::: "memory");

            float acc0 = 0.f, acc1 = 0.f, acc2 = 0.f, acc3 = 0.f;
            auto issue = [&](uint2 (&buf)[8], int j) {
                #pragma unroll
                for (int t = 0; t < 8; ++t) {
                    int s = slds[wslot][g][j + t];
                    buf[t] = *reinterpret_cast<const uint2*>(h + (size_t)s * M + ch0);
                }
            };
            auto consume = [&](uint2 (&buf)[8], int j) {
                #pragma unroll
                for (int t = 0; t < 8; ++t) {
                    float wq = wlds[wslot][g][j + t][hd];
                    wsum += wq;
                    float2 fa = __half22float2(*reinterpret_cast<__half2*>(&buf[t].x));
                    float2 fb = __half22float2(*reinterpret_cast<__half2*>(&buf[t].y));
                    acc0 = fmaf(wq, fa.x, acc0);
                    acc1 = fmaf(wq, fa.y, acc1);
                    acc2 = fmaf(wq, fb.x, acc2);
                    acc3 = fmaf(wq, fb.y, acc3);
                }
            };
            if (cmax > 8) issue(B, 8);
            consume(A, 0);
            if (cmax > 8) {
                if (cmax > 16) issue(A, 16);
                consume(B, 8);
                if (cmax > 16) {
                    if (cmax > 24) issue(B, 24);
                    consume(A, 16);
                    if (cmax > 24) consume(B, 24);
                }
            }
            if (valid) {
                float inv = 1.f / (wsum + EPS_F);
                float4 bb = *reinterpret_cast<const float4*>(bias + ch0);
                float o0 = acc0 * inv + bb.x, o1 = acc1 * inv + bb.y;
                float o2 = acc2 * inv + bb.z, o3 = acc3 * inv + bb.w;
                if constexpr (sizeof(OutT) == 4) {
                    *reinterpret_cast<float4*>((float*)out + (size_t)nd * M + ch0) = make_float4(o0, o1, o2, o3);
                } else {
                    __half2 q0 = __float22half2_rn(make_float2(o0, o1));
                    __half2 q1 = __float22half2_rn(make_float2(o2, o3));
                    uint2 pk;
                    pk.x = *reinterpret_cast<unsigned*>(&q0);
                    pk.y = *reinterpret_cast<unsigned*>(&q1);
                    *reinterpret_cast<uint2*>((__half*)out + (size_t)nd * M + ch0) = pk;
                }
            }
        } else {
            unsigned A[8], B[8];
            #pragma unroll
            for (int t = 0; t < 8; ++t) {
                int s = __shfl(sv, t, 32);
                A[t] = *reinterpret_cast<const unsigned*>(h + (size_t)s * M + ch0);
            }
            {
                float u = aS[sv];
                wlds[wslot][g][lg][0] = (lg < deg) ? __expf(leaky(u + adv[0]))
                                      : (lg == deg) ? __expf(eself[0]) : 0.f;
                slds[wslot][g][lg] = sv;
            }
            asm volatile("s_waitcnt lgkmcnt(0)" ::: "memory");

            float acc0 = 0.f, acc1 = 0.f;
            auto issue = [&](unsigned (&buf)[8], int j) {
                #pragma unroll
                for (int t = 0; t < 8; ++t) {
                    int s = slds[wslot][g][j + t];
                    buf[t] = *reinterpret_cast<const unsigned*>(h + (size_t)s * M + ch0);
                }
            };
            auto consume = [&](unsigned (&buf)[8], int j) {
                #pragma unroll
                for (int t = 0; t < 8; ++t) {
                    float wq = wlds[wslot][g][j + t][0];
                    wsum += wq;
                    float2 fa = __half22float2(*reinterpret_cast<__half2*>(&buf[t]));
                    acc0 = fmaf(wq, fa.x, acc0);
                    acc1 = fmaf(wq, fa.y, acc1);
                }
            };
            if (cmax > 8) issue(B, 8);
            consume(A, 0);
            if (cmax > 8) {
                if (cmax > 16) issue(A, 16);
                consume(B, 8);
                if (cmax > 16) {
                    if (cmax > 24) issue(B, 24);
                    consume(A, 16);
                    if (cmax > 24) consume(B, 24);
                }
            }
            if (valid) {
                float inv = 1.f / (wsum + EPS_F);
                float o0 = acc0 * inv + bias[ch0];
                float o1 = acc1 * inv + bias[ch0 + 1];
                if constexpr (sizeof(OutT) == 4) {
                    *reinterpret_cast<float2*>((float*)out + (size_t)nd * M + ch0) = make_float2(o0, o1);
                } else {
                    __half2 q0 = __float22half2_rn(make_float2(o0, o1));
                    *reinterpret_cast<unsigned*>((__half*)out + (size_t)nd * M + ch0) =
                        *reinterpret_cast<unsigned*>(&q0);
                }
            }
        }
    } else {
        constexpr int CPL64 = M / 64;
        const int ch = lane * CPL64;
        const int hh = ch / C;
        #pragma unroll 1
        for (int i = 0; i < 2; ++i) {
            int fn = (blockIdx.x * 4 + wslot) * 2 + i;
            if (fn >= N) continue;
            float fadv[H], fes[H];
            if constexpr (H == 4) {
                float4 t = *reinterpret_cast<const float4*>(aD + (size_t)fn * 4);
                fadv[0] = t.x; fadv[1] = t.y; fadv[2] = t.z; fadv[3] = t.w;
                float4 u = *reinterpret_cast<const float4*>(aS + (size_t)fn * 4);
                fes[0] = leaky(u.x + t.x); fes[1] = leaky(u.y + t.y);
                fes[2] = leaky(u.z + t.z); fes[3] = leaky(u.w + t.w);
            } else {
                fadv[0] = aD[fn];
                fes[0] = leaky(aS[fn] + fadv[0]);
            }
            int fs0 = off[fn], fs1 = off[fn + 1];
            float m[H], ds[H];
            #pragma unroll
            for (int q = 0; q < H; ++q) { m[q] = fes[q]; ds[q] = 0.f; }
            for (int e = fs0 + lane; e < fs1; e += 64) {
                int s = esrc[e];
                if constexpr (H == 4) {
                    float4 u = *reinterpret_cast<const float4*>(aS + (size_t)s * 4);
                    float evv[4] = {u.x, u.y, u.z, u.w};
                    #pragma unroll
                    for (int q = 0; q < 4; ++q) {
                        float ee = leaky(evv[q] + fadv[q]);
                        float nm = fmaxf(m[q], ee);
                        ds[q] = ds[q] * __expf(m[q] - nm) + __expf(ee - nm);
                        m[q] = nm;
                    }
                } else {
                    float ee = leaky(aS[s] + fadv[0]);
                    float nm = fmaxf(m[0], ee);
                    ds[0] = ds[0] * __expf(m[0] - nm) + __expf(ee - nm);
                    m[0] = nm;
                }
            }
            #pragma unroll
            for (int q = 0; q < H; ++q) {
                #pragma unroll
                for (int d = 1; d < 64; d <<= 1) {
                    float om = __shfl_xor(m[q], d);
                    float od = __shfl_xor(ds[q], d);
                    float nm = fmaxf(m[q], om);
                    ds[q] = ds[q] * __expf(m[q] - nm) + od * __expf(om - nm);
                    m[q] = nm;
                }
                ds[q] += __expf(fes[q] - m[q]);
            }
            float a0 = 0.f, a1 = 0.f;
            for (int e = fs0; e < fs1; ++e) {
                int s = esrc[e];
                float wq = __expf(leaky(aS[(size_t)s * H + hh] + fadv[hh]) - m[hh]);
                if constexpr (CPL64 == 2) {
                    float2 f = __half22float2(*reinterpret_cast<const __half2*>(h + (size_t)s * M + ch));
                    a0 = fmaf(wq, f.x, a0);
                    a1 = fmaf(wq, f.y, a1);
                } else {
                    a0 = fmaf(wq, __half2float(h[(size_t)s * M + ch]), a0);
                }
            }
            {
                float wq = __expf(fes[hh] - m[hh]);
                if constexpr (CPL64 == 2) {
                    float2 f = __half22float2(*reinterpret_cast<const __half2*>(h + (size_t)fn * M + ch));
                    a0 = fmaf(wq, f.x, a0);
                    a1 = fmaf(wq, f.y, a1);
                } else {
                    a0 = fmaf(wq, __half2float(h[(size_t)fn * M + ch]), a0);
                }
            }
            float inv = 1.f / (ds[hh] + EPS_F);
            if constexpr (CPL64 == 2) {
                float o0 = a0 * inv + bias[ch], o1 = a1 * inv + bias[ch + 1];
                if constexpr (sizeof(OutT) == 4) {
                    *reinterpret_cast<float2*>((float*)out + (size_t)fn * M + ch) = make_float2(o0, o1);
                } else {
                    __half2 q0 = __float22half2_rn(make_float2(o0, o1));
                    *reinterpret_cast<unsigned*>((__half*)out + (size_t)fn * M + ch) =
                        *reinterpret_cast<unsigned*>(&q0);
                }
            } else {
                float o0 = a0 * inv + bias[ch];
                if constexpr (sizeof(OutT) == 4) ((float*)out)[(size_t)fn * M + ch] = o0;
                else ((__half*)out)[(size_t)fn * M + ch] = __float2half_rn(o0);
            }
        }
    }
}

// ---------------- launch ----------------

extern "C" void kernel_launch(void* const* d_in, const int* in_sizes, int n_in,
                              void* d_out, int out_size, void* d_ws, size_t ws_size,
                              hipStream_t stream) {
    const float* x   = (const float*)d_in[0];
    const int*   ei  = (const int*)d_in[1];
    const float* W0  = (const float*)d_in[2];
    const float* as0 = (const float*)d_in[3];
    const float* ad0 = (const float*)d_in[4];
    const float* b0  = (const float*)d_in[5];
    const float* W1  = (const float*)d_in[6];
    const float* as1 = (const float*)d_in[7];
    const float* ad1 = (const float*)d_in[8];
    const float* b1  = (const float*)d_in[9];
    const float* W2  = (const float*)d_in[10];
    const float* as2 = (const float*)d_in[11];
    const float* ad2 = (const float*)d_in[12];
    const float* b2  = (const float*)d_in[13];

    const int N = in_sizes[0] / 128;  // 50000
    const int E = in_sizes[1] / 2;    // 800000
    const int* esrc_in = ei;
    const int* edst_in = ei + E;
    const int NBUK = (N + 255) >> 8;  // 196
    const int NBLKB = 256;

    char* w = (char*)d_ws;
    auto carve = [&](size_t bytes) -> char* {
        char* p = w;
        w += (bytes + 255) & ~(size_t)255;
        return p;
    };
    int*    off    = (int*)carve((size_t)(N + 1) * 4);
    int*    es     = (int*)carve((size_t)E * 4);
    int*    cnts   = (int*)carve((size_t)NBUK * NBLKB * 4);
    int*    starts = (int*)carve(((size_t)NBUK * NBLKB + 1) * 4);
    int*    packed = (int*)carve((size_t)E * 4);
    float*  aS     = (float*)carve((size_t)N * 4 * sizeof(float));
    float*  aD     = (float*)carve((size_t)N * 4 * sizeof(float));
    __half* bufH   = (__half*)carve((size_t)N * 128 * sizeof(__half));
    __half* bufO   = (__half*)carve((size_t)N * 128 * sizeof(__half));
    (void)ws_size; (void)n_in; (void)out_size;

    const int GEMM_GRID = (N + 127) / 128;
    const int AGG_GRID = (N + 7) / 8;

    gemm_hist_k<128, 4><<<GEMM_GRID + NBLKB, 256, 0, stream>>>(x, W0, as0, ad0, bufH, aS, aD, N,
                                                               edst_in, E, cnts, GEMM_GRID, NBUK);
    scan_k<<<1, 1024, 0, stream>>>(cnts, starts, NBUK * NBLKB);
    partB_k<<<NBLKB, 256, 0, stream>>>(esrc_in, edst_in, starts, packed, E, NBUK);
    partC_k<<<NBUK, 256, 0, stream>>>(packed, starts, off, es, N, E, NBUK);

    agg_k<4, 32, __half><<<AGG_GRID, 256, 0, stream>>>(bufH, aS, aD, off, es, b0, bufO, N);

    gemm_k<128, 4, __half><<<GEMM_GRID, 256, 0, stream>>>(bufO, W1, as1, ad1, bufH, aS, aD, N);
    agg_k<4, 32, __half><<<AGG_GRID, 256, 0, stream>>>(bufH, aS, aD, off, es, b1, bufO, N);

    gemm_k<64, 1, __half><<<GEMM_GRID, 256, 0, stream>>>(bufO, W2, as2, ad2, bufH, aS, aD, N);
    agg_k<1, 64, float><<<AGG_GRID, 256, 0, stream>>>(bufH, aS, aD, off, es, b2, (float*)d_out, N);
}

// Round 9
// 250.914 us; speedup vs baseline: 1.5426x; 1.0819x over previous
//
#include <hip/hip_runtime.h>
#include <hip/hip_fp16.h>
#include <cstdint>
#include <cstddef>

#define NEG_SLOPE 0.2f
#define EPS_F 1e-16f
#define NBLKB 64

static __device__ __forceinline__ float leaky(float x) { return x > 0.f ? x : NEG_SLOPE * x; }

// ---------------- generic single-block exclusive scan ----------------

__global__ __launch_bounds__(1024) void scan_k(const int* __restrict__ cnt, int* __restrict__ off, int N) {
    __shared__ int wsum[16];
    int tid = threadIdx.x;
    int lane = tid & 63, wid = tid >> 6;
    int running = 0;
    for (int base = 0; base < N; base += 1024) {
        int i = base + tid;
        int v = (i < N) ? cnt[i] : 0;
        int iv = v;
        #pragma unroll
        for (int d = 1; d < 64; d <<= 1) {
            int t = __shfl_up(iv, d);
            if (lane >= d) iv += t;
        }
        if (lane == 63) wsum[wid] = iv;
        __syncthreads();
        if (tid < 16) {
            int s = wsum[tid];
            #pragma unroll
            for (int d = 1; d < 16; d <<= 1) {
                int t = __shfl_up(s, d);
                if (tid >= d) s += t;
            }
            wsum[tid] = s;
        }
        __syncthreads();
        int add = wid ? wsum[wid - 1] : 0;
        if (i < N) off[i + 1] = running + add + iv;
        int ct = wsum[15];
        __syncthreads();
        running += ct;
    }
    if (tid == 0) off[0] = 0;
}

// ---------------- bucketed CSR build ----------------

__global__ __launch_bounds__(256) void partB_k(const int* __restrict__ src, const int* __restrict__ dst,
                                               const int* __restrict__ starts, int* __restrict__ packed,
                                               int E, int nbuk) {
    __shared__ int lcnt[256];
    __shared__ int lbase[256];
    const int blk = blockIdx.x;
    for (int i = threadIdx.x; i < nbuk; i += 256) { lcnt[i] = 0; lbase[i] = starts[i * NBLKB + blk]; }
    __syncthreads();
    const int chunk = (E + NBLKB - 1) / NBLKB;
    const int base = blk * chunk, end = min(base + chunk, E);
    for (int i = base + (int)threadIdx.x; i < end; i += 256) {
        int d = dst[i], s = src[i];
        int b = d >> 8;
        int slot = atomicAdd(&lcnt[b], 1);
        packed[lbase[b] + slot] = s | ((d & 255) << 16);
    }
}

__global__ __launch_bounds__(256) void partC_k(const int* __restrict__ packed, const int* __restrict__ starts,
                                               int* __restrict__ off, int* __restrict__ esrc,
                                               int N, int E, int nbuk) {
    __shared__ int lcnt[256];
    __shared__ int lpre[256];
    const int b = blockIdx.x;
    const int bstart = starts[b * NBLKB];
    const int bend = (b + 1 < nbuk) ? starts[(b + 1) * NBLKB] : E;
    const int tid = threadIdx.x;
    lcnt[tid] = 0;
    __syncthreads();
    for (int i = bstart + tid; i < bend; i += 256) atomicAdd(&lcnt[packed[i] >> 16], 1);
    __syncthreads();
    if (tid < 64) {
        int v0 = lcnt[tid * 4], v1 = lcnt[tid * 4 + 1], v2 = lcnt[tid * 4 + 2], v3 = lcnt[tid * 4 + 3];
        int s = v0 + v1 + v2 + v3;
        int inc = s;
        #pragma unroll
        for (int d = 1; d < 64; d <<= 1) {
            int t = __shfl_up(inc, d);
            if (tid >= d) inc += t;
        }
        int ex = inc - s;
        lpre[tid * 4] = ex;
        lpre[tid * 4 + 1] = ex + v0;
        lpre[tid * 4 + 2] = ex + v0 + v1;
        lpre[tid * 4 + 3] = ex + v0 + v1 + v2;
    }
    __syncthreads();
    const int n0 = b << 8;
    const int nn = min(256, N - n0);
    if (tid < nn) off[n0 + tid] = bstart + lpre[tid];
    if (b == 0 && tid == 0) off[N] = E;
    lcnt[tid] = 0;
    __syncthreads();
    for (int i = bstart + tid; i < bend; i += 256) {
        int p = packed[i];
        int ld = p >> 16;
        int slot = atomicAdd(&lcnt[ld], 1);
        esrc[bstart + lpre[ld] + slot] = p & 0xFFFF;
    }
}

// ---------------- GEMM body (templated input type) ----------------

template <int M, int H, typename XT>
__device__ __forceinline__ void gemm_body(float* xsT, float* wt,
                                          const XT* __restrict__ X, const float* __restrict__ W,
                                          const float* __restrict__ a_s, const float* __restrict__ a_d,
                                          __half* __restrict__ O, float* __restrict__ aS,
                                          float* __restrict__ aD, int N, int bid) {
    constexpr int K = 128, BK = 16, ROWS = 128;
    constexpr int CPT = 8;
    constexpr int CT = M / CPT;
    constexpr int RPT = ROWS / (256 / CT);
    constexpr int XP = ROWS + 4;
    constexpr int C = M / H;
    constexpr int REDW = C / CPT;

    const int tid = threadIdx.x;
    const int cc = tid % CT;
    const int rr = tid / CT;
    const int row0 = bid * ROWS;

    float acc[RPT][CPT];
    #pragma unroll
    for (int r = 0; r < RPT; ++r)
        #pragma unroll
        for (int j = 0; j < CPT; ++j) acc[r][j] = 0.f;

    for (int k0 = 0; k0 < K; k0 += BK) {
        #pragma unroll
        for (int t = tid; t < ROWS * (BK / 4); t += 256) {
            int r = t >> 2;
            int kk = t & 3;
            int row = row0 + r;
            float4 v = make_float4(0.f, 0.f, 0.f, 0.f);
            if (row < N) {
                if constexpr (sizeof(XT) == 2) {
                    uint2 raw = *reinterpret_cast<const uint2*>(&X[(size_t)row * K + k0 + kk * 4]);
                    float2 fa = __half22float2(*reinterpret_cast<__half2*>(&raw.x));
                    float2 fb = __half22float2(*reinterpret_cast<__half2*>(&raw.y));
                    v = make_float4(fa.x, fa.y, fb.x, fb.y);
                } else {
                    v = *reinterpret_cast<const float4*>(&X[(size_t)row * K + k0 + kk * 4]);
                }
            }
            xsT[(kk * 4 + 0) * XP + r] = v.x;
            xsT[(kk * 4 + 1) * XP + r] = v.y;
            xsT[(kk * 4 + 2) * XP + r] = v.z;
            xsT[(kk * 4 + 3) * XP + r] = v.w;
        }
        #pragma unroll
        for (int t = tid; t < BK * (M / 4); t += 256) {
            int c4 = t % (M / 4);
            int k = t / (M / 4);
            *reinterpret_cast<float4*>(&wt[k * M + c4 * 4]) =
                *reinterpret_cast<const float4*>(&W[(size_t)(k0 + k) * M + c4 * 4]);
        }
        __syncthreads();
        #pragma unroll
        for (int k = 0; k < BK; ++k) {
            float xr[RPT];
            #pragma unroll
            for (int r4 = 0; r4 < RPT; r4 += 4) {
                float4 xv = *reinterpret_cast<const float4*>(&xsT[k * XP + rr * RPT + r4]);
                xr[r4 + 0] = xv.x; xr[r4 + 1] = xv.y; xr[r4 + 2] = xv.z; xr[r4 + 3] = xv.w;
            }
            float wv[CPT];
            #pragma unroll
            for (int c4 = 0; c4 < CPT; c4 += 4) {
                float4 w4 = *reinterpret_cast<const float4*>(&wt[k * M + cc * CPT + c4]);
                wv[c4 + 0] = w4.x; wv[c4 + 1] = w4.y; wv[c4 + 2] = w4.z; wv[c4 + 3] = w4.w;
            }
            #pragma unroll
            for (int r = 0; r < RPT; ++r)
                #pragma unroll
                for (int j = 0; j < CPT; ++j)
                    acc[r][j] = fmaf(xr[r], wv[j], acc[r][j]);
        }
        __syncthreads();
    }

    float asr[CPT], adr[CPT];
    #pragma unroll
    for (int c4 = 0; c4 < CPT; c4 += 4) {
        float4 t1 = *reinterpret_cast<const float4*>(a_s + cc * CPT + c4);
        asr[c4 + 0] = t1.x; asr[c4 + 1] = t1.y; asr[c4 + 2] = t1.z; asr[c4 + 3] = t1.w;
        float4 t2 = *reinterpret_cast<const float4*>(a_d + cc * CPT + c4);
        adr[c4 + 0] = t2.x; adr[c4 + 1] = t2.y; adr[c4 + 2] = t2.z; adr[c4 + 3] = t2.w;
    }
    const int head = (cc * CPT) / C;

    #pragma unroll
    for (int r = 0; r < RPT; ++r) {
        int row = row0 + rr * RPT + r;
        float ps = 0.f, pd = 0.f;
        #pragma unroll
        for (int j = 0; j < CPT; ++j) {
            ps = fmaf(acc[r][j], asr[j], ps);
            pd = fmaf(acc[r][j], adr[j], pd);
        }
        #pragma unroll
        for (int d = 1; d < REDW; d <<= 1) {
            ps += __shfl_xor(ps, d);
            pd += __shfl_xor(pd, d);
        }
        if (row < N) {
            __half2 p0 = __float22half2_rn(make_float2(acc[r][0], acc[r][1]));
            __half2 p1 = __float22half2_rn(make_float2(acc[r][2], acc[r][3]));
            __half2 p2 = __float22half2_rn(make_float2(acc[r][4], acc[r][5]));
            __half2 p3 = __float22half2_rn(make_float2(acc[r][6], acc[r][7]));
            uint4 pk;
            pk.x = *reinterpret_cast<unsigned*>(&p0);
            pk.y = *reinterpret_cast<unsigned*>(&p1);
            pk.z = *reinterpret_cast<unsigned*>(&p2);
            pk.w = *reinterpret_cast<unsigned*>(&p3);
            *reinterpret_cast<uint4*>(&O[(size_t)row * M + cc * CPT]) = pk;
            if ((cc & (REDW - 1)) == 0) {
                aS[(size_t)row * H + head] = ps;
                aD[(size_t)row * H + head] = pd;
            }
        }
    }
}

template <int M, int H, typename XT>
__global__ __launch_bounds__(256, 2) void gemm_k(const XT* __restrict__ X, const float* __restrict__ W,
                                                 const float* __restrict__ a_s, const float* __restrict__ a_d,
                                                 __half* __restrict__ O, float* __restrict__ aS,
                                                 float* __restrict__ aD, int N) {
    __shared__ float smem[16 * 132 + 16 * M];
    gemm_body<M, H, XT>(smem, smem + 16 * 132, X, W, a_s, a_d, O, aS, aD, N, blockIdx.x);
}

template <int M, int H>
__global__ __launch_bounds__(256, 2) void gemm_hist_k(const float* __restrict__ X, const float* __restrict__ W,
                                                      const float* __restrict__ a_s, const float* __restrict__ a_d,
                                                      __half* __restrict__ O, float* __restrict__ aS,
                                                      float* __restrict__ aD, int N,
                                                      const int* __restrict__ dst, int E,
                                                      int* __restrict__ cnts, int gemmGrid, int nbuk) {
    __shared__ float smem[16 * 132 + 16 * M];
    if ((int)blockIdx.x < gemmGrid) {
        gemm_body<M, H, float>(smem, smem + 16 * 132, X, W, a_s, a_d, O, aS, aD, N, blockIdx.x);
    } else {
        int* lcnt = (int*)smem;
        const int blk = blockIdx.x - gemmGrid;
        for (int i = threadIdx.x; i < nbuk; i += 256) lcnt[i] = 0;
        __syncthreads();
        const int chunk = (E + NBLKB - 1) / NBLKB;
        const int base = blk * chunk, end = min(base + chunk, E);
        for (int i = base + (int)threadIdx.x; i < end; i += 256) atomicAdd(&lcnt[dst[i] >> 8], 1);
        __syncthreads();
        for (int b = threadIdx.x; b < nbuk; b += 256) cnts[b * NBLKB + blk] = lcnt[b];
    }
}

// ---------------- segment-softmax aggregation: 2 nodes per wave, fp16 payload ----------------
// Fast path: ALL h-row ids come via __shfl of the per-lane esrc value (no slds);
// 16 rows issued before the weight phase, refilled 8 at a time between consumes.

template <int H, int C, typename OutT>
__global__ __launch_bounds__(256) void agg_k(const __half* __restrict__ h, const float* __restrict__ aS,
                                             const float* __restrict__ aD, const int* __restrict__ off,
                                             const int* __restrict__ esrc, const float* __restrict__ bias,
                                             OutT* __restrict__ out, int N) {
    constexpr int M = H * C;
    constexpr int CPL = M / 32;
    __shared__ float wlds[4][2][32][H];
    const int wslot = threadIdx.x >> 6;
    const int lane  = threadIdx.x & 63;
    const int g     = lane >> 5;
    const int lg    = lane & 31;
    const int node  = (blockIdx.x * 4 + wslot) * 2 + g;
    const bool valid = node < N;
    const int nd = valid ? node : N - 1;

    float adv[H], asv[H];
    if constexpr (H == 4) {
        float4 t = *reinterpret_cast<const float4*>(aD + (size_t)nd * 4);
        adv[0] = t.x; adv[1] = t.y; adv[2] = t.z; adv[3] = t.w;
        float4 u = *reinterpret_cast<const float4*>(aS + (size_t)nd * 4);
        asv[0] = u.x; asv[1] = u.y; asv[2] = u.z; asv[3] = u.w;
    } else {
        adv[0] = aD[nd]; asv[0] = aS[nd];
    }
    float eself[H];
    #pragma unroll
    for (int q = 0; q < H; ++q) eself[q] = leaky(asv[q] + adv[q]);

    const int s0 = off[nd], s1 = off[nd + 1];
    const int deg = s1 - s0;

    if (__all(deg < 32)) {
        const int sv = (lg < deg) ? esrc[s0 + lg] : nd;
        const int ch0 = lg * CPL;
        const int hd = ch0 / C;
        const int cnt = deg + 1;
        const int cmax = max(cnt, __shfl_xor(cnt, 32));
        float wsum = 0.f;

        if constexpr (CPL == 4) {
            uint2 A[8], B[8];
            // issue 16 rows before the weight phase, ids via shfl
            #pragma unroll
            for (int t = 0; t < 8; ++t) {
                int s = __shfl(sv, t, 32);
                A[t] = *reinterpret_cast<const uint2*>(h + (size_t)s * M + ch0);
            }
            if (cmax > 8) {
                #pragma unroll
                for (int t = 0; t < 8; ++t) {
                    int s = __shfl(sv, 8 + t, 32);
                    B[t] = *reinterpret_cast<const uint2*>(h + (size_t)s * M + ch0);
                }
            }
            // weight phase (overlaps the h loads)
            {
                float4 u = *reinterpret_cast<const float4*>(aS + (size_t)sv * 4);
                float4 wv;
                if (lg < deg) {
                    wv.x = __expf(leaky(u.x + adv[0]));
                    wv.y = __expf(leaky(u.y + adv[1]));
                    wv.z = __expf(leaky(u.z + adv[2]));
                    wv.w = __expf(leaky(u.w + adv[3]));
                } else if (lg == deg) {
                    wv = make_float4(__expf(eself[0]), __expf(eself[1]), __expf(eself[2]), __expf(eself[3]));
                } else {
                    wv = make_float4(0.f, 0.f, 0.f, 0.f);
                }
                *reinterpret_cast<float4*>(&wlds[wslot][g][lg][0]) = wv;
            }
            asm volatile("s_waitcnt lgkmcnt(0)" ::: "memory");

            float acc0 = 0.f, acc1 = 0.f, acc2 = 0.f, acc3 = 0.f;
            auto refill = [&](uint2 (&buf)[8], int j) {
                #pragma unroll
                for (int t = 0; t < 8; ++t) {
                    int s = __shfl(sv, j + t, 32);
                    buf[t] = *reinterpret_cast<const uint2*>(h + (size_t)s * M + ch0);
                }
            };
            auto consume = [&](uint2 (&buf)[8], int j) {
                #pragma unroll
                for (int t = 0; t < 8; ++t) {
                    float wq = wlds[wslot][g][j + t][hd];
                    wsum += wq;
                    float2 fa = __half22float2(*reinterpret_cast<__half2*>(&buf[t].x));
                    float2 fb = __half22float2(*reinterpret_cast<__half2*>(&buf[t].y));
                    acc0 = fmaf(wq, fa.x, acc0);
                    acc1 = fmaf(wq, fa.y, acc1);
                    acc2 = fmaf(wq, fb.x, acc2);
                    acc3 = fmaf(wq, fb.y, acc3);
                }
            };
            consume(A, 0);
            if (cmax > 8) {
                if (cmax > 16) refill(A, 16);
                consume(B, 8);
                if (cmax > 16) {
                    if (cmax > 24) refill(B, 24);
                    consume(A, 16);
                    if (cmax > 24) consume(B, 24);
                }
            }
            if (valid) {
                float inv = 1.f / (wsum + EPS_F);
                float4 bb = *reinterpret_cast<const float4*>(bias + ch0);
                float o0 = acc0 * inv + bb.x, o1 = acc1 * inv + bb.y;
                float o2 = acc2 * inv + bb.z, o3 = acc3 * inv + bb.w;
                if constexpr (sizeof(OutT) == 4) {
                    *reinterpret_cast<float4*>((float*)out + (size_t)nd * M + ch0) = make_float4(o0, o1, o2, o3);
                } else {
                    __half2 q0 = __float22half2_rn(make_float2(o0, o1));
                    __half2 q1 = __float22half2_rn(make_float2(o2, o3));
                    uint2 pk;
                    pk.x = *reinterpret_cast<unsigned*>(&q0);
                    pk.y = *reinterpret_cast<unsigned*>(&q1);
                    *reinterpret_cast<uint2*>((__half*)out + (size_t)nd * M + ch0) = pk;
                }
            }
        } else {
            unsigned A[8], B[8];
            #pragma unroll
            for (int t = 0; t < 8; ++t) {
                int s = __shfl(sv, t, 32);
                A[t] = *reinterpret_cast<const unsigned*>(h + (size_t)s * M + ch0);
            }
            if (cmax > 8) {
                #pragma unroll
                for (int t = 0; t < 8; ++t) {
                    int s = __shfl(sv, 8 + t, 32);
                    B[t] = *reinterpret_cast<const unsigned*>(h + (size_t)s * M + ch0);
                }
            }
            {
                float u = aS[sv];
                wlds[wslot][g][lg][0] = (lg < deg) ? __expf(leaky(u + adv[0]))
                                      : (lg == deg) ? __expf(eself[0]) : 0.f;
            }
            asm volatile("s_waitcnt lgkmcnt(0)" ::: "memory");

            float acc0 = 0.f, acc1 = 0.f;
            auto refill = [&](unsigned (&buf)[8], int j) {
                #pragma unroll
                for (int t = 0; t < 8; ++t) {
                    int s = __shfl(sv, j + t, 32);
                    buf[t] = *reinterpret_cast<const unsigned*>(h + (size_t)s * M + ch0);
                }
            };
            auto consume = [&](unsigned (&buf)[8], int j) {
                #pragma unroll
                for (int t = 0; t < 8; ++t) {
                    float wq = wlds[wslot][g][j + t][0];
                    wsum += wq;
                    float2 fa = __half22float2(*reinterpret_cast<__half2*>(&buf[t]));
                    acc0 = fmaf(wq, fa.x, acc0);
                    acc1 = fmaf(wq, fa.y, acc1);
                }
            };
            consume(A, 0);
            if (cmax > 8) {
                if (cmax > 16) refill(A, 16);
                consume(B, 8);
                if (cmax > 16) {
                    if (cmax > 24) refill(B, 24);
                    consume(A, 16);
                    if (cmax > 24) consume(B, 24);
                }
            }
            if (valid) {
                float inv = 1.f / (wsum + EPS_F);
                float o0 = acc0 * inv + bias[ch0];
                float o1 = acc1 * inv + bias[ch0 + 1];
                if constexpr (sizeof(OutT) == 4) {
                    *reinterpret_cast<float2*>((float*)out + (size_t)nd * M + ch0) = make_float2(o0, o1);
                } else {
                    __half2 q0 = __float22half2_rn(make_float2(o0, o1));
                    *reinterpret_cast<unsigned*>((__half*)out + (size_t)nd * M + ch0) =
                        *reinterpret_cast<unsigned*>(&q0);
                }
            }
        }
    } else {
        constexpr int CPL64 = M / 64;
        const int ch = lane * CPL64;
        const int hh = ch / C;
        #pragma unroll 1
        for (int i = 0; i < 2; ++i) {
            int fn = (blockIdx.x * 4 + wslot) * 2 + i;
            if (fn >= N) continue;
            float fadv[H], fes[H];
            if constexpr (H == 4) {
                float4 t = *reinterpret_cast<const float4*>(aD + (size_t)fn * 4);
                fadv[0] = t.x; fadv[1] = t.y; fadv[2] = t.z; fadv[3] = t.w;
                float4 u = *reinterpret_cast<const float4*>(aS + (size_t)fn * 4);
                fes[0] = leaky(u.x + t.x); fes[1] = leaky(u.y + t.y);
                fes[2] = leaky(u.z + t.z); fes[3] = leaky(u.w + t.w);
            } else {
                fadv[0] = aD[fn];
                fes[0] = leaky(aS[fn] + fadv[0]);
            }
            int fs0 = off[fn], fs1 = off[fn + 1];
            float m[H], ds[H];
            #pragma unroll
            for (int q = 0; q < H; ++q) { m[q] = fes[q]; ds[q] = 0.f; }
            for (int e = fs0 + lane; e < fs1; e += 64) {
                int s = esrc[e];
                if constexpr (H == 4) {
                    float4 u = *reinterpret_cast<const float4*>(aS + (size_t)s * 4);
                    float evv[4] = {u.x, u.y, u.z, u.w};
                    #pragma unroll
                    for (int q = 0; q < 4; ++q) {
                        float ee = leaky(evv[q] + fadv[q]);
                        float nm = fmaxf(m[q], ee);
                        ds[q] = ds[q] * __expf(m[q] - nm) + __expf(ee - nm);
                        m[q] = nm;
                    }
                } else {
                    float ee = leaky(aS[s] + fadv[0]);
                    float nm = fmaxf(m[0], ee);
                    ds[0] = ds[0] * __expf(m[0] - nm) + __expf(ee - nm);
                    m[0] = nm;
                }
            }
            #pragma unroll
            for (int q = 0; q < H; ++q) {
                #pragma unroll
                for (int d = 1; d < 64; d <<= 1) {
                    float om = __shfl_xor(m[q], d);
                    float od = __shfl_xor(ds[q], d);
                    float nm = fmaxf(m[q], om);
                    ds[q] = ds[q] * __expf(m[q] - nm) + od * __expf(om - nm);
                    m[q] = nm;
                }
                ds[q] += __expf(fes[q] - m[q]);
            }
            float a0 = 0.f, a1 = 0.f;
            for (int e = fs0; e < fs1; ++e) {
                int s = esrc[e];
                float wq = __expf(leaky(aS[(size_t)s * H + hh] + fadv[hh]) - m[hh]);
                if constexpr (CPL64 == 2) {
                    float2 f = __half22float2(*reinterpret_cast<const __half2*>(h + (size_t)s * M + ch));
                    a0 = fmaf(wq, f.x, a0);
                    a1 = fmaf(wq, f.y, a1);
                } else {
                    a0 = fmaf(wq, __half2float(h[(size_t)s * M + ch]), a0);
                }
            }
            {
                float wq = __expf(fes[hh] - m[hh]);
                if constexpr (CPL64 == 2) {
                    float2 f = __half22float2(*reinterpret_cast<const __half2*>(h + (size_t)fn * M + ch));
                    a0 = fmaf(wq, f.x, a0);
                    a1 = fmaf(wq, f.y, a1);
                } else {
                    a0 = fmaf(wq, __half2float(h[(size_t)fn * M + ch]), a0);
                }
            }
            float inv = 1.f / (ds[hh] + EPS_F);
            if constexpr (CPL64 == 2) {
                float o0 = a0 * inv + bias[ch], o1 = a1 * inv + bias[ch + 1];
                if constexpr (sizeof(OutT) == 4) {
                    *reinterpret_cast<float2*>((float*)out + (size_t)fn * M + ch) = make_float2(o0, o1);
                } else {
                    __half2 q0 = __float22half2_rn(make_float2(o0, o1));
                    *reinterpret_cast<unsigned*>((__half*)out + (size_t)fn * M + ch) =
                        *reinterpret_cast<unsigned*>(&q0);
                }
            } else {
                float o0 = a0 * inv + bias[ch];
                if constexpr (sizeof(OutT) == 4) ((float*)out)[(size_t)fn * M + ch] = o0;
                else ((__half*)out)[(size_t)fn * M + ch] = __float2half_rn(o0);
            }
        }
    }
}

// ---------------- launch ----------------

extern "C" void kernel_launch(void* const* d_in, const int* in_sizes, int n_in,
                              void* d_out, int out_size, void* d_ws, size_t ws_size,
                              hipStream_t stream) {
    const float* x   = (const float*)d_in[0];
    const int*   ei  = (const int*)d_in[1];
    const float* W0  = (const float*)d_in[2];
    const float* as0 = (const float*)d_in[3];
    const float* ad0 = (const float*)d_in[4];
    const float* b0  = (const float*)d_in[5];
    const float* W1  = (const float*)d_in[6];
    const float* as1 = (const float*)d_in[7];
    const float* ad1 = (const float*)d_in[8];
    const float* b1  = (const float*)d_in[9];
    const float* W2  = (const float*)d_in[10];
    const float* as2 = (const float*)d_in[11];
    const float* ad2 = (const float*)d_in[12];
    const float* b2  = (const float*)d_in[13];

    const int N = in_sizes[0] / 128;  // 50000
    const int E = in_sizes[1] / 2;    // 800000
    const int* esrc_in = ei;
    const int* edst_in = ei + E;
    const int NBUK = (N + 255) >> 8;  // 196

    char* w = (char*)d_ws;
    auto carve = [&](size_t bytes) -> char* {
        char* p = w;
        w += (bytes + 255) & ~(size_t)255;
        return p;
    };
    int*    off    = (int*)carve((size_t)(N + 1) * 4);
    int*    es     = (int*)carve((size_t)E * 4);
    int*    cnts   = (int*)carve((size_t)NBUK * NBLKB * 4);
    int*    starts = (int*)carve(((size_t)NBUK * NBLKB + 1) * 4);
    int*    packed = (int*)carve((size_t)E * 4);
    float*  aS     = (float*)carve((size_t)N * 4 * sizeof(float));
    float*  aD     = (float*)carve((size_t)N * 4 * sizeof(float));
    __half* bufH   = (__half*)carve((size_t)N * 128 * sizeof(__half));
    __half* bufO   = (__half*)carve((size_t)N * 128 * sizeof(__half));
    (void)ws_size; (void)n_in; (void)out_size;

    const int GEMM_GRID = (N + 127) / 128;
    const int AGG_GRID = (N + 7) / 8;

    gemm_hist_k<128, 4><<<GEMM_GRID + NBLKB, 256, 0, stream>>>(x, W0, as0, ad0, bufH, aS, aD, N,
                                                               edst_in, E, cnts, GEMM_GRID, NBUK);
    scan_k<<<1, 1024, 0, stream>>>(cnts, starts, NBUK * NBLKB);
    partB_k<<<NBLKB, 256, 0, stream>>>(esrc_in, edst_in, starts, packed, E, NBUK);
    partC_k<<<NBUK, 256, 0, stream>>>(packed, starts, off, es, N, E, NBUK);

    agg_k<4, 32, __half><<<AGG_GRID, 256, 0, stream>>>(bufH, aS, aD, off, es, b0, bufO, N);

    gemm_k<128, 4, __half><<<GEMM_GRID, 256, 0, stream>>>(bufO, W1, as1, ad1, bufH, aS, aD, N);
    agg_k<4, 32, __half><<<AGG_GRID, 256, 0, stream>>>(bufH, aS, aD, off, es, b1, bufO, N);

    gemm_k<64, 1, __half><<<GEMM_GRID, 256, 0, stream>>>(bufO, W2, as2, ad2, bufH, aS, aD, N);
    agg_k<1, 64, float><<<AGG_GRID, 256, 0, stream>>>(bufH, aS, aD, off, es, b2, (float*)d_out, N);
}